// Round 4
// baseline (238.193 us; speedup 1.0000x reference)
//
#include <hip/hip_runtime.h>
#include <hip/hip_bf16.h>

// ---------------------------------------------------------------------------
// LogicLayer fused implementation (MI355X / gfx950)
// B=4, N=48, C=16, H=64; CIN={48,64,128,192}, COUT=16
// y3 dominates. Pair-tensors A/B/C = x2@W1-blocks (+b1) precomputed into ws
// so the hot y3 loop only gathers the 6 x3 slices (K=96 MFMA instead of 192);
// 2 tiles per 384-thread block.
// Round-4 fix: s_B/s_C staging wrote only 8 shorts per 16-short stride --
// half of every row was uninitialized LDS. Each thread now writes 2x us8.
// ---------------------------------------------------------------------------

typedef __bf16 bf16x8 __attribute__((ext_vector_type(8)));
typedef unsigned short us8 __attribute__((ext_vector_type(8)));
typedef float f32x4 __attribute__((ext_vector_type(4)));

#define NPAIR 589824  // 4*48*48*64

__device__ __forceinline__ unsigned short f2bf(float f) {
    __hip_bfloat16 h = __float2bfloat16(f);   // RNE
    return __builtin_bit_cast(unsigned short, h);
}
__device__ __forceinline__ unsigned int pk2(float a, float b) {
    return (unsigned int)f2bf(a) | ((unsigned int)f2bf(b) << 16);
}
__device__ __forceinline__ float bf2f(unsigned short u) {
    unsigned int x = ((unsigned int)u) << 16;
    return __builtin_bit_cast(float, x);
}
__device__ __forceinline__ float sigmoidf_(float z) {
    return 1.0f / (1.0f + __expf(-z));
}
__device__ __forceinline__ bf16x8 ld_bf8(const unsigned short* p) {
    return __builtin_bit_cast(bf16x8, *(const us8*)p);
}

// ---------------------------------------------------------------------------
// Phase A: pair tensors for y3 (into workspace).
//   A[b,p,q,h] (fp32) = x2[b,p,q]@W1[  0:16] + x2[b,q,p]@W1[ 64: 80] + b1
//   B[b,p,q,h] (bf16) = x2[b,p,q]@W1[ 32:48] + x2[b,q,p]@W1[ 96:112]
//   C[b,p,q,h] (bf16) = x2[b,p,q]@W1[128:144] + x2[b,q,p]@W1[160:176]
// Block = 4 pairs x 64 h.
// ---------------------------------------------------------------------------
__global__ __launch_bounds__(256) void phaseA_kernel(
    const float* __restrict__ x2, const float* __restrict__ W1,
    const float* __restrict__ b1,
    float* __restrict__ wsA, unsigned short* __restrict__ wsB,
    unsigned short* __restrict__ wsC)
{
    __shared__ float xr[4][32];
    const int t = threadIdx.x;
    if (t < 128) {
        const int pr2 = t >> 5, c = t & 31;
        const int gg = blockIdx.x * 4 + pr2;
        const int bb = gg / 2304, pp2 = gg % 2304, P = pp2 / 48, Q = pp2 % 48;
        const float* base = x2 + (size_t)bb * 36864;
        xr[pr2][c] = (c < 16) ? base[(P * 48 + Q) * 16 + c]
                              : base[(Q * 48 + P) * 16 + (c - 16)];
    }
    __syncthreads();
    const int pr = t >> 6, h = t & 63;
    const int g = blockIdx.x * 4 + pr;
    float a = b1[h], bacc = 0.f, cacc = 0.f;
#pragma unroll
    for (int c = 0; c < 16; ++c) {
        const float xpq = xr[pr][c], xqp = xr[pr][16 + c];
        a    += xpq * W1[(  0 + c) * 64 + h] + xqp * W1[( 64 + c) * 64 + h];
        bacc += xpq * W1[( 32 + c) * 64 + h] + xqp * W1[( 96 + c) * 64 + h];
        cacc += xpq * W1[(128 + c) * 64 + h] + xqp * W1[(160 + c) * 64 + h];
    }
    const size_t o = (size_t)g * 64 + h;
    wsA[o] = a;
    wsB[o] = f2bf(bacc);
    wsC[o] = f2bf(cacc);
}

// ---------------------------------------------------------------------------
// y3 main kernel: 512 blocks x 384 threads (2 tiles x 3 waves), 9 iters.
// Per tile (b,i,j): stage 6 x3 slices (K=96) + B[i,:]/C[j,:]/A[i,j],
// GEMM1 (12 MFMA) + epilogue add A+B+C, relu -> h, GEMM2 (2 MFMA), sigmoid.
// x3 slice order (verified, round 1 passed):
//  s0 x3[b,i,j,k]  s1 x3[b,i,k,j]  s2 x3[b,j,i,k]
//  s3 x3[b,k,i,j]  s4 x3[b,j,k,i]  s5 x3[b,k,j,i]
// W1T row for kk in [0,96): orig = 16 + 32*(kk>>4) + (kk&15).
// ---------------------------------------------------------------------------
__global__ __launch_bounds__(384, 3) void y3_kernel(
    const float* __restrict__ x3,
    const float* __restrict__ W1, const float* __restrict__ W2,
    const float* __restrict__ b2,
    const float* __restrict__ wsA,
    const unsigned short* __restrict__ wsB,
    const unsigned short* __restrict__ wsC,
    float* __restrict__ out)
{
    __shared__ __align__(16) unsigned short w1t[64 * 104];     // [h][kk]
    __shared__ __align__(16) unsigned short w2t[16 * 72];      // [n][k]
    __shared__ __align__(16) unsigned short s_in[2][48 * 104]; // [row][kk]
    __shared__ __align__(16) unsigned short s_h[2][48 * 72];   // [row][h]
    __shared__ __align__(16) unsigned short s_B[2][48 * 72];   // [row][h]
    __shared__ __align__(16) unsigned short s_C[2][48 * 72];
    __shared__ __align__(16) float s_A[2][64];
    __shared__ float s_b2[16];

    const int t = threadIdx.x;
    const int tile = t / 192, tt = t % 192;
    const int w = tt >> 6;                 // wave-in-tile 0..2
    const int lr = t & 15, lg = (t >> 4) & 3;

    // Stage W1T: 64 h x 96 kk -> 3072 uint writes over 384 threads.
#pragma unroll
    for (int p = 0; p < 8; ++p) {
        const int e = p * 384 + t;
        const int h = e & 63, kk = (e >> 6) * 2;
        const int r0 = 16 + ((kk >> 4) << 5) + (kk & 15);
        *(unsigned int*)(w1t + h * 104 + kk) =
            pk2(W1[r0 * 64 + h], W1[(r0 + 1) * 64 + h]);
    }
    // Stage W2T: 512 uint writes -> 2 passes over 384 threads.
#pragma unroll
    for (int p = 0; p < 2; ++p) {
        const int e = p * 384 + t;
        if (e < 512) {
            const int n = e & 15, k2 = e >> 4;
            *(unsigned int*)(w2t + n * 72 + 2 * k2) =
                pk2(W2[(2 * k2) * 16 + n], W2[(2 * k2 + 1) * 16 + n]);
        }
    }
    if (t < 16) s_b2[t] = b2[t];

    const int k48 = tt >> 2, c4 = (tt & 3) * 4;   // x3 staging role
    const int rowB = tt >> 2, part = tt & 3;      // B/C staging role
    unsigned short* sin_t = s_in[tile];
    unsigned short* sh_t  = s_h[tile];
    unsigned short* sB_t  = s_B[tile];
    unsigned short* sC_t  = s_C[tile];

#define ST3(BASE, KSTR, CH) do {                                              \
        const float4 v = *(const float4*)(xb3 + (BASE) + k48 * (KSTR) + c4);  \
        *(uint2*)(sin_t + k48 * 104 + (CH) + c4) =                            \
            make_uint2(pk2(v.x, v.y), pk2(v.z, v.w));                         \
    } while (0)

    for (int it = 0; it < 9; ++it) {
        const int g = blockIdx.x * 18 + it * 2 + tile;
        const int b = g / 2304, pp = g % 2304, i = pp / 48, j = pp % 48;
        const float* xb3 = x3 + (size_t)b * 1769472;
        __syncthreads();   // previous iteration's LDS readers done
        ST3(i * 36864 + j * 768, 16,     0);   // x3[b,i,j,k]
        ST3(i * 36864 + j * 16,  768,   16);   // x3[b,i,k,j]
        ST3(j * 36864 + i * 768, 16,    32);   // x3[b,j,i,k]
        ST3(i * 768   + j * 16,  36864, 48);   // x3[b,k,i,j]
        ST3(j * 36864 + i * 16,  768,   64);   // x3[b,j,k,i]
        ST3(j * 768   + i * 16,  36864, 80);   // x3[b,k,j,i]
        {   // B[i,row]/C[j,row]: 64 bf16 per row = 4 threads x 16 shorts
            // (round-4 fix: TWO us8 writes per thread, not one)
            const size_t ofB = ((size_t)(b * 48 + i) * 48 + rowB) * 64 + part * 16;
            const size_t ofC = ((size_t)(b * 48 + j) * 48 + rowB) * 64 + part * 16;
            *(us8*)(sB_t + rowB * 72 + part * 16)     = *(const us8*)(wsB + ofB);
            *(us8*)(sB_t + rowB * 72 + part * 16 + 8) = *(const us8*)(wsB + ofB + 8);
            *(us8*)(sC_t + rowB * 72 + part * 16)     = *(const us8*)(wsC + ofC);
            *(us8*)(sC_t + rowB * 72 + part * 16 + 8) = *(const us8*)(wsC + ofC + 8);
        }
        if (tt < 16)
            *(float4*)(s_A[tile] + tt * 4) =
                *(const float4*)(wsA + ((size_t)(b * 48 + i) * 48 + j) * 64 + tt * 4);
        __syncthreads();

        // GEMM1: [48 rows x K=96] @ W1T -> 4 h-blocks per wave-tile
        f32x4 acc[4];
#pragma unroll
        for (int n = 0; n < 4; ++n) acc[n] = f32x4{0.f, 0.f, 0.f, 0.f};
        const unsigned short* pa = sin_t + (16 * w + lr) * 104 + lg * 8;
        const unsigned short* pb = w1t + lr * 104 + lg * 8;
#pragma unroll
        for (int ks = 0; ks < 3; ++ks) {
            const bf16x8 a = ld_bf8(pa + ks * 32);
#pragma unroll
            for (int n = 0; n < 4; ++n)
                acc[n] = __builtin_amdgcn_mfma_f32_16x16x32_bf16(
                    a, ld_bf8(pb + n * 16 * 104 + ks * 32), acc[n], 0, 0, 0);
        }
        // Epilogue 1: + A[i,j] + B[i,row] + C[j,row], ReLU, -> s_h (bf16)
        const int hr = 16 * w + 4 * lg;
        float Af[4];
#pragma unroll
        for (int n = 0; n < 4; ++n) Af[n] = s_A[tile][16 * n + lr];
#pragma unroll
        for (int n = 0; n < 4; ++n) {
#pragma unroll
            for (int r = 0; r < 4; ++r) {
                const int row = hr + r;
                const float v = acc[n][r] + Af[n]
                    + bf2f(sB_t[row * 72 + 16 * n + lr])
                    + bf2f(sC_t[row * 72 + 16 * n + lr]);
                sh_t[row * 72 + 16 * n + lr] = f2bf(fmaxf(v, 0.f));
            }
        }
        __syncthreads();
        // GEMM2: [48 rows x K=64] @ W2T
        f32x4 o = {0.f, 0.f, 0.f, 0.f};
#pragma unroll
        for (int ks = 0; ks < 2; ++ks)
            o = __builtin_amdgcn_mfma_f32_16x16x32_bf16(
                ld_bf8(sh_t + (16 * w + lr) * 72 + ks * 32 + lg * 8),
                ld_bf8(w2t + lr * 72 + ks * 32 + lg * 8), o, 0, 0, 0);
        float* op = out + (size_t)g * 768;
        const float b2v = s_b2[lr];
#pragma unroll
        for (int r = 0; r < 4; ++r)
            op[(hr + r) * 16 + lr] = sigmoidf_(o[r] + b2v);
    }
#undef ST3
}

// ---------------------------------------------------------------------------
// Round-1 y3 (fallback if workspace too small) — verified correct.
// ---------------------------------------------------------------------------
template <int NK>
__device__ __forceinline__ void mlp_head(
    const unsigned short* lds_in, const unsigned short* lds_w1t,
    const unsigned short* lds_w2t, const float* lds_b1, const float* lds_b2,
    unsigned short* lds_h, float* outp)
{
    constexpr int S = NK * 32 + 8;
    const int t = threadIdx.x;
    const int w = t >> 6, lr = t & 15, lg = (t >> 4) & 3;
    f32x4 acc0 = {0.f, 0.f, 0.f, 0.f};
    f32x4 acc1 = acc0, acc2 = acc0, acc3 = acc0;
    const unsigned short* pa = lds_in + (16 * w + lr) * S + lg * 8;
    const unsigned short* pb = lds_w1t + lr * S + lg * 8;
#pragma unroll
    for (int ks = 0; ks < NK; ++ks) {
        bf16x8 a = ld_bf8(pa + ks * 32);
        acc0 = __builtin_amdgcn_mfma_f32_16x16x32_bf16(a, ld_bf8(pb + 0 * 16 * S + ks * 32), acc0, 0, 0, 0);
        acc1 = __builtin_amdgcn_mfma_f32_16x16x32_bf16(a, ld_bf8(pb + 1 * 16 * S + ks * 32), acc1, 0, 0, 0);
        acc2 = __builtin_amdgcn_mfma_f32_16x16x32_bf16(a, ld_bf8(pb + 2 * 16 * S + ks * 32), acc2, 0, 0, 0);
        acc3 = __builtin_amdgcn_mfma_f32_16x16x32_bf16(a, ld_bf8(pb + 3 * 16 * S + ks * 32), acc3, 0, 0, 0);
    }
    const int hrow = 16 * w + lg * 4;
#pragma unroll
    for (int r = 0; r < 4; ++r) {
        lds_h[(hrow + r) * 72 +  0 + lr] = f2bf(fmaxf(acc0[r] + lds_b1[ 0 + lr], 0.f));
        lds_h[(hrow + r) * 72 + 16 + lr] = f2bf(fmaxf(acc1[r] + lds_b1[16 + lr], 0.f));
        lds_h[(hrow + r) * 72 + 32 + lr] = f2bf(fmaxf(acc2[r] + lds_b1[32 + lr], 0.f));
        lds_h[(hrow + r) * 72 + 48 + lr] = f2bf(fmaxf(acc3[r] + lds_b1[48 + lr], 0.f));
    }
    __syncthreads();
    f32x4 o = {0.f, 0.f, 0.f, 0.f};
#pragma unroll
    for (int ks = 0; ks < 2; ++ks) {
        bf16x8 a = ld_bf8(lds_h + (16 * w + lr) * 72 + ks * 32 + lg * 8);
        bf16x8 b = ld_bf8(lds_w2t + lr * 72 + ks * 32 + lg * 8);
        o = __builtin_amdgcn_mfma_f32_16x16x32_bf16(a, b, o, 0, 0, 0);
    }
    const float b2v = lds_b2[lr];
#pragma unroll
    for (int r = 0; r < 4; ++r)
        outp[(hrow + r) * 16 + lr] = sigmoidf_(o[r] + b2v);
}

__global__ __launch_bounds__(192) void y3_fallback_kernel(
    const float* __restrict__ x2, const float* __restrict__ x3,
    const float* __restrict__ W1, const float* __restrict__ b1,
    const float* __restrict__ W2, const float* __restrict__ b2,
    float* __restrict__ out)
{
    __shared__ __align__(16) unsigned short lds_in[48 * 200];
    __shared__ __align__(16) unsigned short lds_w1t[64 * 200];
    __shared__ __align__(16) unsigned short lds_w2t[16 * 72];
    __shared__ __align__(16) unsigned short lds_h[48 * 72];
    __shared__ float lds_b1[64];
    __shared__ float lds_b2[16];
    const int t = threadIdx.x;
#pragma unroll 4
    for (int p = 0; p < 32; ++p) {
        int e = p * 192 + t;
        int h = e & 63, c2 = e >> 6;
        *(unsigned int*)(lds_w1t + h * 200 + 2 * c2) =
            pk2(W1[(2 * c2) * 64 + h], W1[(2 * c2 + 1) * 64 + h]);
    }
    for (int p = 0; p < 3; ++p) {
        int e = p * 192 + t;
        if (e < 512) {
            int n = e & 15, k2 = e >> 4;
            *(unsigned int*)(lds_w2t + n * 72 + 2 * k2) =
                pk2(W2[(2 * k2) * 16 + n], W2[(2 * k2 + 1) * 16 + n]);
        }
    }
    if (t < 64) lds_b1[t] = b1[t];
    if (t < 16) lds_b2[t] = b2[t];
    const int k = t >> 2, c4 = (t & 3) * 4;
#define STAGE3(PTR, BASE, KSTR, CH) do {                                       \
        const float4 v = *(const float4*)((PTR) + (BASE) + k * (KSTR) + c4);   \
        *(uint2*)(lds_in + k * 200 + (CH) + c4) =                              \
            make_uint2(pk2(v.x, v.y), pk2(v.z, v.w));                          \
    } while (0)
    for (int it = 0; it < 9; ++it) {
        const int g = blockIdx.x * 9 + it;
        const int b = g / 2304, rg = g % 2304, i = rg / 48, j = rg % 48;
        const float* xb2 = x2 + b * 36864;
        const float* xb3 = x3 + b * 1769472;
        __syncthreads();
        STAGE3(xb2, i * 768 + j * 16, 0,       0);
        STAGE3(xb3, i * 36864 + j * 768, 16,   16);
        STAGE3(xb2, i * 768, 16,               32);
        STAGE3(xb3, i * 36864 + j * 16, 768,   48);
        STAGE3(xb2, j * 768 + i * 16, 0,       64);
        STAGE3(xb3, j * 36864 + i * 768, 16,   80);
        STAGE3(xb2, i * 16, 768,               96);
        STAGE3(xb3, i * 768 + j * 16, 36864,   112);
        STAGE3(xb2, j * 768, 16,               128);
        STAGE3(xb3, j * 36864 + i * 16, 768,   144);
        STAGE3(xb2, j * 16, 768,               160);
        STAGE3(xb3, j * 768 + i * 16, 36864,   176);
        __syncthreads();
        mlp_head<6>(lds_in, lds_w1t, lds_w2t, lds_b1, lds_b2, lds_h,
                    out + (size_t)g * 768);
    }
#undef STAGE3
}

// ---------------------------------------------------------------------------
// y2 (unchanged, verified)
// ---------------------------------------------------------------------------
__global__ __launch_bounds__(192) void y2_kernel(
    const float* __restrict__ x1, const float* __restrict__ x2,
    const float* __restrict__ x3,
    const float* __restrict__ W1, const float* __restrict__ b1,
    const float* __restrict__ W2, const float* __restrict__ b2,
    float* __restrict__ out)
{
    __shared__ __align__(16) unsigned short lds_in[48 * 136];
    __shared__ __align__(16) unsigned short lds_w1t[64 * 136];
    __shared__ __align__(16) unsigned short lds_w2t[16 * 72];
    __shared__ __align__(16) unsigned short lds_h[48 * 72];
    __shared__ float lds_b1[64];
    __shared__ float lds_b2[16];
    const int t = threadIdx.x;
    const int b = blockIdx.x / 48, i = blockIdx.x % 48;
#pragma unroll 2
    for (int p = 0; p < 22; ++p) {
        int e = p * 192 + t;
        if (e < 4096) {
            int h = e & 63, c2 = e >> 6;
            *(unsigned int*)(lds_w1t + h * 136 + 2 * c2) =
                pk2(W1[(2 * c2) * 64 + h], W1[(2 * c2 + 1) * 64 + h]);
        }
    }
    for (int p = 0; p < 3; ++p) {
        int e = p * 192 + t;
        if (e < 512) {
            int n = e & 15, k2 = e >> 4;
            *(unsigned int*)(lds_w2t + n * 72 + 2 * k2) =
                pk2(W2[(2 * k2) * 16 + n], W2[(2 * k2 + 1) * 16 + n]);
        }
    }
    if (t < 64) lds_b1[t] = b1[t];
    if (t < 16) lds_b2[t] = b2[t];
    const int j = t >> 2, c4 = (t & 3) * 4;
    const float* xb2 = x2 + b * 36864;
#define STAGE2(PTR, BASE, JSTR, CH) do {                                       \
        const float4 v = *(const float4*)((PTR) + (BASE) + j * (JSTR) + c4);   \
        *(uint2*)(lds_in + j * 136 + (CH) + c4) =                              \
            make_uint2(pk2(v.x, v.y), pk2(v.z, v.w));                          \
    } while (0)
    STAGE2(x1, b * 768 + i * 16, 0,  0);
    STAGE2(xb2, i * 768, 16,         16);
    STAGE2(x1, b * 768, 16,          64);
    STAGE2(xb2, i * 16, 768,         80);
#undef STAGE2
    {
        const float* pa = x3 + b * 1769472 + (i * 48 + j) * 768 + c4;
        const float* pb = x3 + b * 1769472 + (j * 48 + i) * 768 + c4;
        float exa[4], faa[4], exb[4], fab[4];
#pragma unroll
        for (int u = 0; u < 4; ++u) {
            exa[u] = -__builtin_inff(); faa[u] = __builtin_inff();
            exb[u] = -__builtin_inff(); fab[u] = __builtin_inff();
        }
        for (int kk = 0; kk < 48; ++kk) {
            const bool m = (i != j) & (i != kk) & (j != kk);
            const float4 va = *(const float4*)(pa + kk * 16);
            const float4 vb = *(const float4*)(pb + kk * 16);
            const float av[4] = {va.x, va.y, va.z, va.w};
            const float bv[4] = {vb.x, vb.y, vb.z, vb.w};
#pragma unroll
            for (int u = 0; u < 4; ++u) {
                exa[u] = fmaxf(exa[u], m ? av[u] : 0.f);
                faa[u] = fminf(faa[u], m ? av[u] : 1.f);
                exb[u] = fmaxf(exb[u], m ? bv[u] : 0.f);
                fab[u] = fminf(fab[u], m ? bv[u] : 1.f);
            }
        }
#pragma unroll
        for (int u = 0; u < 4; ++u) {
            const int c = c4 + u;
            *(unsigned int*)(lds_in + j * 136 + 32 + 2 * c) = pk2(exa[u], faa[u]);
            *(unsigned int*)(lds_in + j * 136 + 96 + 2 * c) = pk2(exb[u], fab[u]);
        }
    }
    __syncthreads();
    mlp_head<4>(lds_in, lds_w1t, lds_w2t, lds_b1, lds_b2, lds_h,
                out + (size_t)blockIdx.x * 768);
}

// ---------------------------------------------------------------------------
// y0 + y1 (unchanged, verified)
// ---------------------------------------------------------------------------
__global__ __launch_bounds__(128) void y01_kernel(
    const float* __restrict__ x0, const float* __restrict__ x1,
    const float* __restrict__ x2,
    const float* __restrict__ W1_0, const float* __restrict__ b1_0,
    const float* __restrict__ W2_0, const float* __restrict__ b2_0,
    const float* __restrict__ W1_1, const float* __restrict__ b1_1,
    const float* __restrict__ W2_1, const float* __restrict__ b2_1,
    float* __restrict__ out)
{
    __shared__ float w1[64 * 64];
    __shared__ float w2[64 * 16];
    __shared__ float bb1[64];
    __shared__ float bb2[16];
    __shared__ float hbuf[48 * 64];
    const int t = threadIdx.x;
    if (blockIdx.x < 4) {
        const int b = blockIdx.x;
        for (int e = t; e < 4096; e += 128) w1[e] = W1_1[e];
        for (int e = t; e < 1024; e += 128) w2[e] = W2_1[e];
        if (t < 64) bb1[t] = b1_1[t];
        if (t < 16) bb2[t] = b2_1[t];
        __syncthreads();
        if (t < 96) {
            const int i = t % 48, half = t / 48;
            float ex[16], fa[16];
#pragma unroll
            for (int c = 0; c < 16; ++c) { ex[c] = -__builtin_inff(); fa[c] = __builtin_inff(); }
            const float* px = x2 + (b * 48 + i) * 768;
            for (int jj = 0; jj < 48; ++jj) {
                const bool m = (jj != i);
#pragma unroll
                for (int c = 0; c < 16; ++c) {
                    const float v = px[jj * 16 + c];
                    ex[c] = fmaxf(ex[c], m ? v : 0.f);
                    fa[c] = fminf(fa[c], m ? v : 1.f);
                }
            }
            float t1[64];
#pragma unroll
            for (int c = 0; c < 16; ++c) t1[c] = x0[b * 16 + c];
#pragma unroll
            for (int c = 0; c < 16; ++c) t1[16 + c] = x1[(b * 48 + i) * 16 + c];
#pragma unroll
            for (int c = 0; c < 16; ++c) { t1[32 + 2 * c] = ex[c]; t1[33 + 2 * c] = fa[c]; }
            float hh[32];
#pragma unroll
            for (int u = 0; u < 32; ++u) hh[u] = bb1[half * 32 + u];
#pragma unroll
            for (int c = 0; c < 64; ++c) {
                const float tc = t1[c];
#pragma unroll
                for (int u = 0; u < 32; ++u)
                    hh[u] = fmaf(tc, w1[c * 64 + half * 32 + u], hh[u]);
            }
#pragma unroll
            for (int u = 0; u < 32; ++u) hbuf[i * 64 + half * 32 + u] = fmaxf(hh[u], 0.f);
        }
        __syncthreads();
        if (t < 48) {
            const int i = t;
            float acc[16];
#pragma unroll
            for (int o = 0; o < 16; ++o) acc[o] = bb2[o];
            for (int h2 = 0; h2 < 64; ++h2) {
                const float vh = hbuf[i * 64 + h2];
#pragma unroll
                for (int o = 0; o < 16; ++o) acc[o] = fmaf(vh, w2[h2 * 16 + o], acc[o]);
            }
#pragma unroll
            for (int o = 0; o < 16; ++o)
                out[64 + (b * 48 + i) * 16 + o] = sigmoidf_(acc[o]);
        }
    } else {
        const int b = blockIdx.x - 4;
        for (int e = t; e < 3072; e += 128) w1[e] = W1_0[e];
        for (int e = t; e < 1024; e += 128) w2[e] = W2_0[e];
        if (t < 64) bb1[t] = b1_0[t];
        if (t < 16) bb2[t] = b2_0[t];
        __syncthreads();
        if (t < 64) {
            float ex[16], fa[16];
#pragma unroll
            for (int c = 0; c < 16; ++c) { ex[c] = -__builtin_inff(); fa[c] = __builtin_inff(); }
            const float* px = x1 + b * 768;
            for (int n = 0; n < 48; ++n) {
#pragma unroll
                for (int c = 0; c < 16; ++c) {
                    const float v = px[n * 16 + c];
                    ex[c] = fmaxf(ex[c], v);
                    fa[c] = fminf(fa[c], v);
                }
            }
            float t0[48];
#pragma unroll
            for (int c = 0; c < 16; ++c) t0[c] = x0[b * 16 + c];
#pragma unroll
            for (int c = 0; c < 16; ++c) { t0[16 + 2 * c] = ex[c]; t0[17 + 2 * c] = fa[c]; }
            float a = bb1[t];
#pragma unroll
            for (int c = 0; c < 48; ++c) a = fmaf(t0[c], w1[c * 64 + t], a);
            hbuf[t] = fmaxf(a, 0.f);
        }
        __syncthreads();
        if (t < 16) {
            float a = bb2[t];
            for (int h2 = 0; h2 < 64; ++h2) a = fmaf(hbuf[h2], w2[h2 * 16 + t], a);
            out[b * 16 + t] = sigmoidf_(a);
        }
    }
}

// ---------------------------------------------------------------------------
extern "C" void kernel_launch(void* const* d_in, const int* in_sizes, int n_in,
                              void* d_out, int out_size, void* d_ws, size_t ws_size,
                              hipStream_t stream) {
    (void)in_sizes; (void)n_in; (void)out_size;
    const float* x0 = (const float*)d_in[0];
    const float* x1 = (const float*)d_in[1];
    const float* x2 = (const float*)d_in[2];
    const float* x3 = (const float*)d_in[3];
    const float* W1_0 = (const float*)d_in[4];
    const float* b1_0 = (const float*)d_in[5];
    const float* W2_0 = (const float*)d_in[6];
    const float* b2_0 = (const float*)d_in[7];
    const float* W1_1 = (const float*)d_in[8];
    const float* b1_1 = (const float*)d_in[9];
    const float* W2_1 = (const float*)d_in[10];
    const float* b2_1 = (const float*)d_in[11];
    const float* W1_2 = (const float*)d_in[12];
    const float* b1_2 = (const float*)d_in[13];
    const float* W2_2 = (const float*)d_in[14];
    const float* b2_2 = (const float*)d_in[15];
    const float* W1_3 = (const float*)d_in[16];
    const float* b1_3 = (const float*)d_in[17];
    const float* W2_3 = (const float*)d_in[18];
    const float* b2_3 = (const float*)d_in[19];
    float* out = (float*)d_out;

    // Output layout: y0 [0,64) | y1 [64,3136) | y2 [3136,150592) | y3 [150592,...)
    // ws layout: A fp32 [NPAIR] | B bf16 [NPAIR] | C bf16 [NPAIR] = 8*NPAIR bytes
    const size_t ws_need = (size_t)8 * NPAIR;
    if (ws_size >= ws_need) {
        float* wsA = (float*)d_ws;
        unsigned short* wsB = (unsigned short*)d_ws + 2 * NPAIR;
        unsigned short* wsC = wsB + NPAIR;
        phaseA_kernel<<<2304, 256, 0, stream>>>(x2, W1_3, b1_3, wsA, wsB, wsC);
        y3_kernel<<<512, 384, 0, stream>>>(x3, W1_3, W2_3, b2_3,
                                           wsA, wsB, wsC, out + 150592);
    } else {
        y3_fallback_kernel<<<1024, 192, 0, stream>>>(x2, x3, W1_3, b1_3, W2_3, b2_3,
                                                     out + 150592);
    }
    y2_kernel<<<192, 192, 0, stream>>>(x1, x2, x3, W1_2, b1_2, W2_2, b2_2, out + 3136);
    y01_kernel<<<8, 128, 0, stream>>>(x0, x1, x2, W1_0, b1_0, W2_0, b2_0,
                                      W1_1, b1_1, W2_1, b2_1, out);
}

// Round 5
// 227.740 us; speedup vs baseline: 1.0459x; 1.0459x over previous
//
#include <hip/hip_runtime.h>
#include <hip/hip_bf16.h>

// ---------------------------------------------------------------------------
// LogicLayer fused implementation (MI355X / gfx950)
// B=4, N=48, C=16, H=64; CIN={48,64,128,192}, COUT=16
// Round-5: barrier-free register-resident y3/y2 MLPs via swapped-operand MFMA:
//   GEMM1: acc = mfma(A=W1T-frag, B=x-frag)  -> D[ch][row]; x-frags are 8
//   contiguous floats per lane, loaded global->reg (no LDS staging/barriers).
//   GEMM2: channel permutation ch(lg,e,m)=16*(e>>1)+4lg+2*(e&1)+m applied to
//   BOTH h-values (in-register) and W2 fragment -> no LDS round trip.
// y2 split: red3 reduction kernel (ws-cached bf16) + register MLP.
// ---------------------------------------------------------------------------

typedef __bf16 bf16x8 __attribute__((ext_vector_type(8)));
typedef unsigned short us8 __attribute__((ext_vector_type(8)));
typedef float f32x4 __attribute__((ext_vector_type(4)));

#define NPAIR 589824   // 4*48*48*64
#define NRED3 294912   // 4*48*48*32 (shorts)

__device__ __forceinline__ unsigned short f2bf(float f) {
    __hip_bfloat16 h = __float2bfloat16(f);   // RNE
    return __builtin_bit_cast(unsigned short, h);
}
__device__ __forceinline__ unsigned int pk2(float a, float b) {
    return (unsigned int)f2bf(a) | ((unsigned int)f2bf(b) << 16);
}
__device__ __forceinline__ float bflo(unsigned int u) {
    return __builtin_bit_cast(float, u << 16);
}
__device__ __forceinline__ float bfhi(unsigned int u) {
    return __builtin_bit_cast(float, u & 0xffff0000u);
}
__device__ __forceinline__ float sigmoidf_(float z) {
    return 1.0f / (1.0f + __expf(-z));
}
__device__ __forceinline__ bf16x8 ld_bf8(const unsigned short* p) {
    return __builtin_bit_cast(bf16x8, *(const us8*)p);
}
__device__ __forceinline__ bf16x8 pack8(float4 a, float4 b) {
    us8 u;
    u[0] = f2bf(a.x); u[1] = f2bf(a.y); u[2] = f2bf(a.z); u[3] = f2bf(a.w);
    u[4] = f2bf(b.x); u[5] = f2bf(b.y); u[6] = f2bf(b.z); u[7] = f2bf(b.w);
    return __builtin_bit_cast(bf16x8, u);
}

// ---------------------------------------------------------------------------
// Phase A: pair tensors for y3 (verified round 4).
//   A[b,p,q,h] (fp32) = x2[b,p,q]@W1[0:16]   + x2[b,q,p]@W1[64:80]  + b1
//   B[b,p,q,h] (bf16) = x2[b,p,q]@W1[32:48]  + x2[b,q,p]@W1[96:112]
//   C[b,p,q,h] (bf16) = x2[b,p,q]@W1[128:144]+ x2[b,q,p]@W1[160:176]
// ---------------------------------------------------------------------------
__global__ __launch_bounds__(256) void phaseA_kernel(
    const float* __restrict__ x2, const float* __restrict__ W1,
    const float* __restrict__ b1,
    float* __restrict__ wsA, unsigned short* __restrict__ wsB,
    unsigned short* __restrict__ wsC)
{
    __shared__ float xr[4][32];
    const int t = threadIdx.x;
    if (t < 128) {
        const int pr2 = t >> 5, c = t & 31;
        const int gg = blockIdx.x * 4 + pr2;
        const int bb = gg / 2304, pp2 = gg % 2304, P = pp2 / 48, Q = pp2 % 48;
        const float* base = x2 + (size_t)bb * 36864;
        xr[pr2][c] = (c < 16) ? base[(P * 48 + Q) * 16 + c]
                              : base[(Q * 48 + P) * 16 + (c - 16)];
    }
    __syncthreads();
    const int pr = t >> 6, h = t & 63;
    const int g = blockIdx.x * 4 + pr;
    float a = b1[h], bacc = 0.f, cacc = 0.f;
#pragma unroll
    for (int c = 0; c < 16; ++c) {
        const float xpq = xr[pr][c], xqp = xr[pr][16 + c];
        a    += xpq * W1[(  0 + c) * 64 + h] + xqp * W1[( 64 + c) * 64 + h];
        bacc += xpq * W1[( 32 + c) * 64 + h] + xqp * W1[( 96 + c) * 64 + h];
        cacc += xpq * W1[(128 + c) * 64 + h] + xqp * W1[(160 + c) * 64 + h];
    }
    const size_t o = (size_t)g * 64 + h;
    wsA[o] = a;
    wsB[o] = f2bf(bacc);
    wsC[o] = f2bf(cacc);
}

// ---------------------------------------------------------------------------
// y3: 2304 blocks x 192 thr (3 waves), 4 tiles each, barrier-free main loop.
// Swapped GEMM1: acc[n] = mfma(w1f[n][ks], xf[ks]) -> acc[n][r] =
//   h[ch=16n+4lg+r][row=16w+lr].  K-chan kappa=32ks+8lg+e -> slice
//   q=2ks+(lg>>1), c=8(lg&1)+e of x3 perms (verified order r1..r4).
// Epilogue adds A[i,j][ch]+B[i,row][ch]+C[j,row][ch], relu.
// GEMM2 swapped with ch(lg,e,m)=16*(e>>1)+4lg+2*(e&1)+m permutation on both
// sides; D2 -> out[row=16w+lr][o=4lg+r], float4 store.
// ---------------------------------------------------------------------------
__global__ __launch_bounds__(192, 3) void y3_kernel(
    const float* __restrict__ x3,
    const float* __restrict__ W1, const float* __restrict__ W2,
    const float* __restrict__ b2,
    const float* __restrict__ wsA,
    const unsigned short* __restrict__ wsB,
    const unsigned short* __restrict__ wsC,
    float* __restrict__ out)
{
    __shared__ __align__(16) unsigned short w1t[64 * 104];   // [h][kk], one-time
    const int t = threadIdx.x;
    const int w = t >> 6, lane = t & 63, lr = lane & 15, lg = lane >> 4;

    // Stage W1T (96 K-chans; orig row = 16 + 32*(kk>>4) + (kk&15)): 3072 uints.
#pragma unroll
    for (int p = 0; p < 16; ++p) {
        const int e = p * 192 + t;
        const int h = e & 63, kk = (e >> 6) * 2;
        const int r0 = 16 + ((kk >> 4) << 5) + (kk & 15);
        *(unsigned int*)(w1t + h * 104 + kk) =
            pk2(W1[r0 * 64 + h], W1[(r0 + 1) * 64 + h]);
    }
    __syncthreads();   // only barrier in the kernel

    bf16x8 w1f[4][3];
#pragma unroll
    for (int n = 0; n < 4; ++n)
#pragma unroll
        for (int ks = 0; ks < 3; ++ks)
            w1f[n][ks] = ld_bf8(w1t + (16 * n + lr) * 104 + 32 * ks + 8 * lg);

    bf16x8 w2f[2];
#pragma unroll
    for (int m = 0; m < 2; ++m) {
        us8 u;
#pragma unroll
        for (int e = 0; e < 8; ++e) {
            const int ch = 16 * (e >> 1) + 4 * lg + 2 * (e & 1) + m;
            u[e] = f2bf(W2[ch * 16 + lr]);
        }
        w2f[m] = __builtin_bit_cast(bf16x8, u);
    }
    const float4 b2v = *(const float4*)(b2 + 4 * lg);
    const int row = 16 * w + lr;
    const int c0 = 8 * (lg & 1);
    const bool hi = (lg >> 1) != 0;

    for (int it = 0; it < 4; ++it) {
        const int g = blockIdx.x * 4 + it;
        const int b = g / 2304, pp = g % 2304, i = pp / 48, j = pp % 48;
        const float* xb3 = x3 + (size_t)b * 1769472;
        // slice row-bases (floats); q0..q5 = perms (i,j,k)(i,k,j)(j,i,k)(k,i,j)(j,k,i)(k,j,i)
        const int sb0 = i * 36864 + j * 768 + row * 16;
        const int sb1 = i * 36864 + row * 768 + j * 16;
        const int sb2 = j * 36864 + i * 768 + row * 16;
        const int sb3 = row * 36864 + i * 768 + j * 16;
        const int sb4 = j * 36864 + row * 768 + i * 16;
        const int sb5 = row * 36864 + j * 768 + i * 16;
        const float* p0 = xb3 + (hi ? sb1 : sb0) + c0;
        const float* p1 = xb3 + (hi ? sb3 : sb2) + c0;
        const float* p2 = xb3 + (hi ? sb5 : sb4) + c0;
        const bf16x8 xf0 = pack8(*(const float4*)p0, *(const float4*)(p0 + 4));
        const bf16x8 xf1 = pack8(*(const float4*)p1, *(const float4*)(p1 + 4));
        const bf16x8 xf2 = pack8(*(const float4*)p2, *(const float4*)(p2 + 4));

        f32x4 acc[4];
#pragma unroll
        for (int n = 0; n < 4; ++n) {
            acc[n] = f32x4{0.f, 0.f, 0.f, 0.f};
            acc[n] = __builtin_amdgcn_mfma_f32_16x16x32_bf16(w1f[n][0], xf0, acc[n], 0, 0, 0);
            acc[n] = __builtin_amdgcn_mfma_f32_16x16x32_bf16(w1f[n][1], xf1, acc[n], 0, 0, 0);
            acc[n] = __builtin_amdgcn_mfma_f32_16x16x32_bf16(w1f[n][2], xf2, acc[n], 0, 0, 0);
        }
        // Epilogue: + A + B + C, relu (direct L2 reads, ch = 16n+4lg+r)
        const size_t baseB = ((size_t)((b * 48 + i) * 48 + row)) * 64 + 4 * lg;
        const size_t baseC = ((size_t)((b * 48 + j) * 48 + row)) * 64 + 4 * lg;
        const size_t baseA = ((size_t)((b * 48 + i) * 48 + j)) * 64 + 4 * lg;
#pragma unroll
        for (int n = 0; n < 4; ++n) {
            const uint2 Bu = *(const uint2*)(wsB + baseB + 16 * n);
            const uint2 Cu = *(const uint2*)(wsC + baseC + 16 * n);
            const float4 Au = *(const float4*)(wsA + baseA + 16 * n);
            acc[n][0] = fmaxf(acc[n][0] + Au.x + bflo(Bu.x) + bflo(Cu.x), 0.f);
            acc[n][1] = fmaxf(acc[n][1] + Au.y + bfhi(Bu.x) + bfhi(Cu.x), 0.f);
            acc[n][2] = fmaxf(acc[n][2] + Au.z + bflo(Bu.y) + bflo(Cu.y), 0.f);
            acc[n][3] = fmaxf(acc[n][3] + Au.w + bfhi(Bu.y) + bfhi(Cu.y), 0.f);
        }
        // GEMM2 (in-register, permuted channels)
        bf16x8 hf[2];
#pragma unroll
        for (int m = 0; m < 2; ++m) {
            us8 u;
#pragma unroll
            for (int e = 0; e < 8; ++e)
                u[e] = f2bf(acc[e >> 1][2 * (e & 1) + m]);
            hf[m] = __builtin_bit_cast(bf16x8, u);
        }
        f32x4 o2 = {0.f, 0.f, 0.f, 0.f};
        o2 = __builtin_amdgcn_mfma_f32_16x16x32_bf16(w2f[0], hf[0], o2, 0, 0, 0);
        o2 = __builtin_amdgcn_mfma_f32_16x16x32_bf16(w2f[1], hf[1], o2, 0, 0, 0);
        float4 ov;
        ov.x = sigmoidf_(o2[0] + b2v.x);
        ov.y = sigmoidf_(o2[1] + b2v.y);
        ov.z = sigmoidf_(o2[2] + b2v.z);
        ov.w = sigmoidf_(o2[3] + b2v.w);
        *(float4*)(out + (size_t)g * 768 + row * 16 + 4 * lg) = ov;
    }
}

// ---------------------------------------------------------------------------
// red3: masked (pairwise-distinct) max/min over k of x3 -> bf16 [b,i,j][32]
// interleaved (ex,fa) per channel.  147456 slots, 576 blocks x 256.
// ---------------------------------------------------------------------------
__global__ __launch_bounds__(256) void red3_kernel(
    const float* __restrict__ x3, unsigned short* __restrict__ red3)
{
    const int slot = blockIdx.x * 256 + threadIdx.x;
    const int c = slot & 15;
    const int q = slot >> 4;          // pi*48 + j, pi = b*48+i
    const int j = q % 48, pi = q / 48, i = pi % 48;
    const float* p = x3 + (size_t)q * 768 + c;
    float ex = -__builtin_inff(), fa = __builtin_inff();
    const bool mij = (i != j);
    for (int k = 0; k < 48; ++k) {
        const bool m = mij & (k != i) & (k != j);
        const float v = p[k * 16];
        ex = fmaxf(ex, m ? v : 0.f);
        fa = fminf(fa, m ? v : 1.f);
    }
    *(unsigned int*)(red3 + (size_t)q * 32 + 2 * c) = pk2(ex, fa);
}

// ---------------------------------------------------------------------------
// y2 MLP (register style, barrier-free loop): 192 blocks=(b,i) x 192 thr.
// Rows = j.  K=128 segs: [x1_i|x2_ij|red3_ij(32)|x1_j|x2_ji|red3_ji(32)].
// kappa=32ks+8lg+e -> seg=2ks+(lg>>1), c=8(lg&1)+e.
// ---------------------------------------------------------------------------
__global__ __launch_bounds__(192, 3) void y2_mlp_kernel(
    const float* __restrict__ x1, const float* __restrict__ x2,
    const float* __restrict__ W1, const float* __restrict__ b1,
    const float* __restrict__ W2, const float* __restrict__ b2,
    const unsigned short* __restrict__ red3, float* __restrict__ out)
{
    __shared__ __align__(16) unsigned short w1t[64 * 136];
    const int t = threadIdx.x;
    const int w = t >> 6, lane = t & 63, lr = lane & 15, lg = lane >> 4;

#pragma unroll
    for (int p = 0; p < 22; ++p) {
        const int e = p * 192 + t;
        if (e < 4096) {
            const int h = e & 63, k2 = e >> 6;
            *(unsigned int*)(w1t + h * 136 + 2 * k2) =
                pk2(W1[(2 * k2) * 64 + h], W1[(2 * k2 + 1) * 64 + h]);
        }
    }
    __syncthreads();

    bf16x8 w1f[4][4];
#pragma unroll
    for (int n = 0; n < 4; ++n)
#pragma unroll
        for (int ks = 0; ks < 4; ++ks)
            w1f[n][ks] = ld_bf8(w1t + (16 * n + lr) * 136 + 32 * ks + 8 * lg);

    bf16x8 w2f[2];
#pragma unroll
    for (int m = 0; m < 2; ++m) {
        us8 u;
#pragma unroll
        for (int e = 0; e < 8; ++e) {
            const int ch = 16 * (e >> 1) + 4 * lg + 2 * (e & 1) + m;
            u[e] = f2bf(W2[ch * 16 + lr]);
        }
        w2f[m] = __builtin_bit_cast(bf16x8, u);
    }
    float4 b1v[4];
#pragma unroll
    for (int n = 0; n < 4; ++n) b1v[n] = *(const float4*)(b1 + 16 * n + 4 * lg);
    const float4 b2v = *(const float4*)(b2 + 4 * lg);

    const int bq = blockIdx.x;                 // b*48 + i
    const int b = bq / 48, i = bq % 48;
    const float* x2b = x2 + (size_t)b * 36864;
    const int row = 16 * w + lr;               // = j
    const int j = row;
    const int c0 = 8 * (lg & 1);
    const bool hi = (lg >> 1) != 0;

    const float* a0 = hi ? (x2b + (i * 48 + j) * 16 + c0) : (x1 + (b * 48 + i) * 16 + c0);
    const float* a2 = hi ? (x2b + (j * 48 + i) * 16 + c0) : (x1 + (b * 48 + j) * 16 + c0);
    const unsigned short* r1 = red3 + ((size_t)(b * 48 + i) * 48 + j) * 32 + (hi ? 16 : 0) + c0;
    const unsigned short* r3 = red3 + ((size_t)(b * 48 + j) * 48 + i) * 32 + (hi ? 16 : 0) + c0;

    const bf16x8 xf0 = pack8(*(const float4*)a0, *(const float4*)(a0 + 4));
    const bf16x8 xf1 = ld_bf8(r1);
    const bf16x8 xf2 = pack8(*(const float4*)a2, *(const float4*)(a2 + 4));
    const bf16x8 xf3 = ld_bf8(r3);

    f32x4 acc[4];
#pragma unroll
    for (int n = 0; n < 4; ++n) {
        acc[n] = f32x4{0.f, 0.f, 0.f, 0.f};
        acc[n] = __builtin_amdgcn_mfma_f32_16x16x32_bf16(w1f[n][0], xf0, acc[n], 0, 0, 0);
        acc[n] = __builtin_amdgcn_mfma_f32_16x16x32_bf16(w1f[n][1], xf1, acc[n], 0, 0, 0);
        acc[n] = __builtin_amdgcn_mfma_f32_16x16x32_bf16(w1f[n][2], xf2, acc[n], 0, 0, 0);
        acc[n] = __builtin_amdgcn_mfma_f32_16x16x32_bf16(w1f[n][3], xf3, acc[n], 0, 0, 0);
    }
#pragma unroll
    for (int n = 0; n < 4; ++n) {
        acc[n][0] = fmaxf(acc[n][0] + b1v[n].x, 0.f);
        acc[n][1] = fmaxf(acc[n][1] + b1v[n].y, 0.f);
        acc[n][2] = fmaxf(acc[n][2] + b1v[n].z, 0.f);
        acc[n][3] = fmaxf(acc[n][3] + b1v[n].w, 0.f);
    }
    bf16x8 hf[2];
#pragma unroll
    for (int m = 0; m < 2; ++m) {
        us8 u;
#pragma unroll
        for (int e = 0; e < 8; ++e)
            u[e] = f2bf(acc[e >> 1][2 * (e & 1) + m]);
        hf[m] = __builtin_bit_cast(bf16x8, u);
    }
    f32x4 o2 = {0.f, 0.f, 0.f, 0.f};
    o2 = __builtin_amdgcn_mfma_f32_16x16x32_bf16(w2f[0], hf[0], o2, 0, 0, 0);
    o2 = __builtin_amdgcn_mfma_f32_16x16x32_bf16(w2f[1], hf[1], o2, 0, 0, 0);
    float4 ov;
    ov.x = sigmoidf_(o2[0] + b2v.x);
    ov.y = sigmoidf_(o2[1] + b2v.y);
    ov.z = sigmoidf_(o2[2] + b2v.z);
    ov.w = sigmoidf_(o2[3] + b2v.w);
    *(float4*)(out + ((size_t)bq * 48 + row) * 16 + 4 * lg) = ov;
}

// ---------------------------------------------------------------------------
// Fallback paths (verified round 1/4), used only if workspace too small.
// ---------------------------------------------------------------------------
template <int NK>
__device__ __forceinline__ void mlp_head(
    const unsigned short* lds_in, const unsigned short* lds_w1t,
    const unsigned short* lds_w2t, const float* lds_b1, const float* lds_b2,
    unsigned short* lds_h, float* outp)
{
    constexpr int S = NK * 32 + 8;
    const int t = threadIdx.x;
    const int w = t >> 6, lr = t & 15, lg = (t >> 4) & 3;
    f32x4 acc0 = {0.f, 0.f, 0.f, 0.f};
    f32x4 acc1 = acc0, acc2 = acc0, acc3 = acc0;
    const unsigned short* pa = lds_in + (16 * w + lr) * S + lg * 8;
    const unsigned short* pb = lds_w1t + lr * S + lg * 8;
#pragma unroll
    for (int ks = 0; ks < NK; ++ks) {
        bf16x8 a = ld_bf8(pa + ks * 32);
        acc0 = __builtin_amdgcn_mfma_f32_16x16x32_bf16(a, ld_bf8(pb + 0 * 16 * S + ks * 32), acc0, 0, 0, 0);
        acc1 = __builtin_amdgcn_mfma_f32_16x16x32_bf16(a, ld_bf8(pb + 1 * 16 * S + ks * 32), acc1, 0, 0, 0);
        acc2 = __builtin_amdgcn_mfma_f32_16x16x32_bf16(a, ld_bf8(pb + 2 * 16 * S + ks * 32), acc2, 0, 0, 0);
        acc3 = __builtin_amdgcn_mfma_f32_16x16x32_bf16(a, ld_bf8(pb + 3 * 16 * S + ks * 32), acc3, 0, 0, 0);
    }
    const int hrow = 16 * w + lg * 4;
#pragma unroll
    for (int r = 0; r < 4; ++r) {
        lds_h[(hrow + r) * 72 +  0 + lr] = f2bf(fmaxf(acc0[r] + lds_b1[ 0 + lr], 0.f));
        lds_h[(hrow + r) * 72 + 16 + lr] = f2bf(fmaxf(acc1[r] + lds_b1[16 + lr], 0.f));
        lds_h[(hrow + r) * 72 + 32 + lr] = f2bf(fmaxf(acc2[r] + lds_b1[32 + lr], 0.f));
        lds_h[(hrow + r) * 72 + 48 + lr] = f2bf(fmaxf(acc3[r] + lds_b1[48 + lr], 0.f));
    }
    __syncthreads();
    f32x4 o = {0.f, 0.f, 0.f, 0.f};
#pragma unroll
    for (int ks = 0; ks < 2; ++ks) {
        bf16x8 a = ld_bf8(lds_h + (16 * w + lr) * 72 + ks * 32 + lg * 8);
        bf16x8 b = ld_bf8(lds_w2t + lr * 72 + ks * 32 + lg * 8);
        o = __builtin_amdgcn_mfma_f32_16x16x32_bf16(a, b, o, 0, 0, 0);
    }
    const float b2v = lds_b2[lr];
#pragma unroll
    for (int r = 0; r < 4; ++r)
        outp[(hrow + r) * 16 + lr] = sigmoidf_(o[r] + b2v);
}

__global__ __launch_bounds__(192) void y3_fallback_kernel(
    const float* __restrict__ x2, const float* __restrict__ x3,
    const float* __restrict__ W1, const float* __restrict__ b1,
    const float* __restrict__ W2, const float* __restrict__ b2,
    float* __restrict__ out)
{
    __shared__ __align__(16) unsigned short lds_in[48 * 200];
    __shared__ __align__(16) unsigned short lds_w1t[64 * 200];
    __shared__ __align__(16) unsigned short lds_w2t[16 * 72];
    __shared__ __align__(16) unsigned short lds_h[48 * 72];
    __shared__ float lds_b1[64];
    __shared__ float lds_b2[16];
    const int t = threadIdx.x;
#pragma unroll 4
    for (int p = 0; p < 32; ++p) {
        int e = p * 192 + t;
        int h = e & 63, c2 = e >> 6;
        *(unsigned int*)(lds_w1t + h * 200 + 2 * c2) =
            pk2(W1[(2 * c2) * 64 + h], W1[(2 * c2 + 1) * 64 + h]);
    }
    for (int p = 0; p < 3; ++p) {
        int e = p * 192 + t;
        if (e < 512) {
            int n = e & 15, k2 = e >> 4;
            *(unsigned int*)(lds_w2t + n * 72 + 2 * k2) =
                pk2(W2[(2 * k2) * 16 + n], W2[(2 * k2 + 1) * 16 + n]);
        }
    }
    if (t < 64) lds_b1[t] = b1[t];
    if (t < 16) lds_b2[t] = b2[t];
    const int k = t >> 2, c4 = (t & 3) * 4;
#define STAGE3(PTR, BASE, KSTR, CH) do {                                       \
        const float4 v = *(const float4*)((PTR) + (BASE) + k * (KSTR) + c4);   \
        *(uint2*)(lds_in + k * 200 + (CH) + c4) =                              \
            make_uint2(pk2(v.x, v.y), pk2(v.z, v.w));                          \
    } while (0)
    for (int it = 0; it < 9; ++it) {
        const int g = blockIdx.x * 9 + it;
        const int b = g / 2304, rg = g % 2304, i = rg / 48, j = rg % 48;
        const float* xb2 = x2 + b * 36864;
        const float* xb3 = x3 + b * 1769472;
        __syncthreads();
        STAGE3(xb2, i * 768 + j * 16, 0,       0);
        STAGE3(xb3, i * 36864 + j * 768, 16,   16);
        STAGE3(xb2, i * 768, 16,               32);
        STAGE3(xb3, i * 36864 + j * 16, 768,   48);
        STAGE3(xb2, j * 768 + i * 16, 0,       64);
        STAGE3(xb3, j * 36864 + i * 768, 16,   80);
        STAGE3(xb2, i * 16, 768,               96);
        STAGE3(xb3, i * 768 + j * 16, 36864,   112);
        STAGE3(xb2, j * 768, 16,               128);
        STAGE3(xb3, j * 36864 + i * 16, 768,   144);
        STAGE3(xb2, j * 16, 768,               160);
        STAGE3(xb3, j * 768 + i * 16, 36864,   176);
        __syncthreads();
        mlp_head<6>(lds_in, lds_w1t, lds_w2t, lds_b1, lds_b2, lds_h,
                    out + (size_t)g * 768);
    }
#undef STAGE3
}

__global__ __launch_bounds__(192) void y2_kernel(
    const float* __restrict__ x1, const float* __restrict__ x2,
    const float* __restrict__ x3,
    const float* __restrict__ W1, const float* __restrict__ b1,
    const float* __restrict__ W2, const float* __restrict__ b2,
    float* __restrict__ out)
{
    __shared__ __align__(16) unsigned short lds_in[48 * 136];
    __shared__ __align__(16) unsigned short lds_w1t[64 * 136];
    __shared__ __align__(16) unsigned short lds_w2t[16 * 72];
    __shared__ __align__(16) unsigned short lds_h[48 * 72];
    __shared__ float lds_b1[64];
    __shared__ float lds_b2[16];
    const int t = threadIdx.x;
    const int b = blockIdx.x / 48, i = blockIdx.x % 48;
#pragma unroll 2
    for (int p = 0; p < 22; ++p) {
        int e = p * 192 + t;
        if (e < 4096) {
            int h = e & 63, c2 = e >> 6;
            *(unsigned int*)(lds_w1t + h * 136 + 2 * c2) =
                pk2(W1[(2 * c2) * 64 + h], W1[(2 * c2 + 1) * 64 + h]);
        }
    }
    for (int p = 0; p < 3; ++p) {
        int e = p * 192 + t;
        if (e < 512) {
            int n = e & 15, k2 = e >> 4;
            *(unsigned int*)(lds_w2t + n * 72 + 2 * k2) =
                pk2(W2[(2 * k2) * 16 + n], W2[(2 * k2 + 1) * 16 + n]);
        }
    }
    if (t < 64) lds_b1[t] = b1[t];
    if (t < 16) lds_b2[t] = b2[t];
    const int j = t >> 2, c4 = (t & 3) * 4;
    const float* xb2 = x2 + b * 36864;
#define STAGE2(PTR, BASE, JSTR, CH) do {                                       \
        const float4 v = *(const float4*)((PTR) + (BASE) + j * (JSTR) + c4);   \
        *(uint2*)(lds_in + j * 136 + (CH) + c4) =                              \
            make_uint2(pk2(v.x, v.y), pk2(v.z, v.w));                          \
    } while (0)
    STAGE2(x1, b * 768 + i * 16, 0,  0);
    STAGE2(xb2, i * 768, 16,         16);
    STAGE2(x1, b * 768, 16,          64);
    STAGE2(xb2, i * 16, 768,         80);
#undef STAGE2
    {
        const float* pa = x3 + b * 1769472 + (i * 48 + j) * 768 + c4;
        const float* pb = x3 + b * 1769472 + (j * 48 + i) * 768 + c4;
        float exa[4], faa[4], exb[4], fab[4];
#pragma unroll
        for (int u = 0; u < 4; ++u) {
            exa[u] = -__builtin_inff(); faa[u] = __builtin_inff();
            exb[u] = -__builtin_inff(); fab[u] = __builtin_inff();
        }
        for (int kk = 0; kk < 48; ++kk) {
            const bool m = (i != j) & (i != kk) & (j != kk);
            const float4 va = *(const float4*)(pa + kk * 16);
            const float4 vb = *(const float4*)(pb + kk * 16);
            const float av[4] = {va.x, va.y, va.z, va.w};
            const float bv[4] = {vb.x, vb.y, vb.z, vb.w};
#pragma unroll
            for (int u = 0; u < 4; ++u) {
                exa[u] = fmaxf(exa[u], m ? av[u] : 0.f);
                faa[u] = fminf(faa[u], m ? av[u] : 1.f);
                exb[u] = fmaxf(exb[u], m ? bv[u] : 0.f);
                fab[u] = fminf(fab[u], m ? bv[u] : 1.f);
            }
        }
#pragma unroll
        for (int u = 0; u < 4; ++u) {
            const int c = c4 + u;
            *(unsigned int*)(lds_in + j * 136 + 32 + 2 * c) = pk2(exa[u], faa[u]);
            *(unsigned int*)(lds_in + j * 136 + 96 + 2 * c) = pk2(exb[u], fab[u]);
        }
    }
    __syncthreads();
    mlp_head<4>(lds_in, lds_w1t, lds_w2t, lds_b1, lds_b2, lds_h,
                out + (size_t)blockIdx.x * 768);
}

// ---------------------------------------------------------------------------
// y0 + y1: vectorized loads (round-5), logic unchanged.
// ---------------------------------------------------------------------------
__global__ __launch_bounds__(128) void y01_kernel(
    const float* __restrict__ x0, const float* __restrict__ x1,
    const float* __restrict__ x2,
    const float* __restrict__ W1_0, const float* __restrict__ b1_0,
    const float* __restrict__ W2_0, const float* __restrict__ b2_0,
    const float* __restrict__ W1_1, const float* __restrict__ b1_1,
    const float* __restrict__ W2_1, const float* __restrict__ b2_1,
    float* __restrict__ out)
{
    __shared__ float w1[64 * 64];
    __shared__ float w2[64 * 16];
    __shared__ float bb1[64];
    __shared__ float bb2[16];
    __shared__ float hbuf[48 * 64];
    const int t = threadIdx.x;
    if (blockIdx.x < 4) {
        const int b = blockIdx.x;
        for (int e = t; e < 4096; e += 128) w1[e] = W1_1[e];
        for (int e = t; e < 1024; e += 128) w2[e] = W2_1[e];
        if (t < 64) bb1[t] = b1_1[t];
        if (t < 16) bb2[t] = b2_1[t];
        __syncthreads();
        if (t < 96) {
            const int i = t % 48, half = t / 48;
            float ex[16], fa[16];
#pragma unroll
            for (int c = 0; c < 16; ++c) { ex[c] = -__builtin_inff(); fa[c] = __builtin_inff(); }
            const float* px = x2 + (b * 48 + i) * 768;
            for (int jj = 0; jj < 48; ++jj) {
                const bool m = (jj != i);
                const float4 q0 = *(const float4*)(px + jj * 16);
                const float4 q1 = *(const float4*)(px + jj * 16 + 4);
                const float4 q2 = *(const float4*)(px + jj * 16 + 8);
                const float4 q3 = *(const float4*)(px + jj * 16 + 12);
                const float vals[16] = {q0.x,q0.y,q0.z,q0.w, q1.x,q1.y,q1.z,q1.w,
                                        q2.x,q2.y,q2.z,q2.w, q3.x,q3.y,q3.z,q3.w};
#pragma unroll
                for (int c = 0; c < 16; ++c) {
                    ex[c] = fmaxf(ex[c], m ? vals[c] : 0.f);
                    fa[c] = fminf(fa[c], m ? vals[c] : 1.f);
                }
            }
            float t1[64];
#pragma unroll
            for (int c = 0; c < 16; ++c) t1[c] = x0[b * 16 + c];
#pragma unroll
            for (int c = 0; c < 16; ++c) t1[16 + c] = x1[(b * 48 + i) * 16 + c];
#pragma unroll
            for (int c = 0; c < 16; ++c) { t1[32 + 2 * c] = ex[c]; t1[33 + 2 * c] = fa[c]; }
            float hh[32];
#pragma unroll
            for (int u = 0; u < 32; ++u) hh[u] = bb1[half * 32 + u];
#pragma unroll
            for (int c = 0; c < 64; ++c) {
                const float tc = t1[c];
#pragma unroll
                for (int u = 0; u < 32; ++u)
                    hh[u] = fmaf(tc, w1[c * 64 + half * 32 + u], hh[u]);
            }
#pragma unroll
            for (int u = 0; u < 32; ++u) hbuf[i * 64 + half * 32 + u] = fmaxf(hh[u], 0.f);
        }
        __syncthreads();
        if (t < 48) {
            const int i = t;
            float acc[16];
#pragma unroll
            for (int o = 0; o < 16; ++o) acc[o] = bb2[o];
            for (int h2 = 0; h2 < 64; ++h2) {
                const float vh = hbuf[i * 64 + h2];
#pragma unroll
                for (int o = 0; o < 16; ++o) acc[o] = fmaf(vh, w2[h2 * 16 + o], acc[o]);
            }
#pragma unroll
            for (int o = 0; o < 16; ++o)
                out[64 + (b * 48 + i) * 16 + o] = sigmoidf_(acc[o]);
        }
    } else {
        const int b = blockIdx.x - 4;
        for (int e = t; e < 3072; e += 128) w1[e] = W1_0[e];
        for (int e = t; e < 1024; e += 128) w2[e] = W2_0[e];
        if (t < 64) bb1[t] = b1_0[t];
        if (t < 16) bb2[t] = b2_0[t];
        __syncthreads();
        if (t < 64) {
            float ex[16], fa[16];
#pragma unroll
            for (int c = 0; c < 16; ++c) { ex[c] = -__builtin_inff(); fa[c] = __builtin_inff(); }
            const float* px = x1 + b * 768;
            for (int n = 0; n < 48; ++n) {
                const float4 q0 = *(const float4*)(px + n * 16);
                const float4 q1 = *(const float4*)(px + n * 16 + 4);
                const float4 q2 = *(const float4*)(px + n * 16 + 8);
                const float4 q3 = *(const float4*)(px + n * 16 + 12);
                const float vals[16] = {q0.x,q0.y,q0.z,q0.w, q1.x,q1.y,q1.z,q1.w,
                                        q2.x,q2.y,q2.z,q2.w, q3.x,q3.y,q3.z,q3.w};
#pragma unroll
                for (int c = 0; c < 16; ++c) {
                    ex[c] = fmaxf(ex[c], vals[c]);
                    fa[c] = fminf(fa[c], vals[c]);
                }
            }
            float t0[48];
#pragma unroll
            for (int c = 0; c < 16; ++c) t0[c] = x0[b * 16 + c];
#pragma unroll
            for (int c = 0; c < 16; ++c) { t0[16 + 2 * c] = ex[c]; t0[17 + 2 * c] = fa[c]; }
            float a = bb1[t];
#pragma unroll
            for (int c = 0; c < 48; ++c) a = fmaf(t0[c], w1[c * 64 + t], a);
            hbuf[t] = fmaxf(a, 0.f);
        }
        __syncthreads();
        if (t < 16) {
            float a = bb2[t];
            for (int h2 = 0; h2 < 64; ++h2) a = fmaf(hbuf[h2], w2[h2 * 16 + t], a);
            out[b * 16 + t] = sigmoidf_(a);
        }
    }
}

// ---------------------------------------------------------------------------
extern "C" void kernel_launch(void* const* d_in, const int* in_sizes, int n_in,
                              void* d_out, int out_size, void* d_ws, size_t ws_size,
                              hipStream_t stream) {
    (void)in_sizes; (void)n_in; (void)out_size;
    const float* x0 = (const float*)d_in[0];
    const float* x1 = (const float*)d_in[1];
    const float* x2 = (const float*)d_in[2];
    const float* x3 = (const float*)d_in[3];
    const float* W1_0 = (const float*)d_in[4];
    const float* b1_0 = (const float*)d_in[5];
    const float* W2_0 = (const float*)d_in[6];
    const float* b2_0 = (const float*)d_in[7];
    const float* W1_1 = (const float*)d_in[8];
    const float* b1_1 = (const float*)d_in[9];
    const float* W2_1 = (const float*)d_in[10];
    const float* b2_1 = (const float*)d_in[11];
    const float* W1_2 = (const float*)d_in[12];
    const float* b1_2 = (const float*)d_in[13];
    const float* W2_2 = (const float*)d_in[14];
    const float* b2_2 = (const float*)d_in[15];
    const float* W1_3 = (const float*)d_in[16];
    const float* b1_3 = (const float*)d_in[17];
    const float* W2_3 = (const float*)d_in[18];
    const float* b2_3 = (const float*)d_in[19];
    float* out = (float*)d_out;

    // Output layout: y0 [0,64) | y1 [64,3136) | y2 [3136,150592) | y3 [150592,...)
    // ws layout (shorts): A fp32 [2*NPAIR] | B [NPAIR] | C [NPAIR] | red3 [NRED3]
    const size_t ws_need = (size_t)8 * NPAIR + (size_t)2 * NRED3;
    if (ws_size >= ws_need) {
        float* wsA = (float*)d_ws;
        unsigned short* wsB = (unsigned short*)d_ws + 2 * NPAIR;
        unsigned short* wsC = wsB + NPAIR;
        unsigned short* red3 = (unsigned short*)d_ws + 4 * NPAIR;
        phaseA_kernel<<<2304, 256, 0, stream>>>(x2, W1_3, b1_3, wsA, wsB, wsC);
        y3_kernel<<<2304, 192, 0, stream>>>(x3, W1_3, W2_3, b2_3,
                                            wsA, wsB, wsC, out + 150592);
        red3_kernel<<<576, 256, 0, stream>>>(x3, red3);
        y2_mlp_kernel<<<192, 192, 0, stream>>>(x1, x2, W1_2, b1_2, W2_2, b2_2,
                                               red3, out + 3136);
    } else {
        y3_fallback_kernel<<<1024, 192, 0, stream>>>(x2, x3, W1_3, b1_3, W2_3, b2_3,
                                                     out + 150592);
        y2_kernel<<<192, 192, 0, stream>>>(x1, x2, x3, W1_2, b1_2, W2_2, b2_2,
                                           out + 3136);
    }
    y01_kernel<<<8, 128, 0, stream>>>(x0, x1, x2, W1_0, b1_0, W2_0, b2_0,
                                      W1_1, b1_1, W2_1, b2_1, out);
}

// Round 6
// 199.350 us; speedup vs baseline: 1.1948x; 1.1424x over previous
//
#include <hip/hip_runtime.h>
#include <hip/hip_bf16.h>

// ---------------------------------------------------------------------------
// LogicLayer fused implementation (MI355X / gfx950)
// B=4, N=48, C=16, H=64; CIN={48,64,128,192}, COUT=16
// Round-6: y01 rewrite (was 74us @ 0.1% occupancy, VGPR-spill + serial-load
// latency).  y1 now uses the verified swapped-MFMA register template with an
// in-LDS red2 phase; y0 is a cooperative 64-thread LDS MLP.  red3 gets
// unroll-8.  phaseA / y3 / y2_mlp unchanged (verified round 5).
// ---------------------------------------------------------------------------

typedef __bf16 bf16x8 __attribute__((ext_vector_type(8)));
typedef unsigned short us8 __attribute__((ext_vector_type(8)));
typedef float f32x4 __attribute__((ext_vector_type(4)));

#define NPAIR 589824   // 4*48*48*64
#define NRED3 294912   // 4*48*48*32 (shorts)

__device__ __forceinline__ unsigned short f2bf(float f) {
    __hip_bfloat16 h = __float2bfloat16(f);   // RNE
    return __builtin_bit_cast(unsigned short, h);
}
__device__ __forceinline__ unsigned int pk2(float a, float b) {
    return (unsigned int)f2bf(a) | ((unsigned int)f2bf(b) << 16);
}
__device__ __forceinline__ float bflo(unsigned int u) {
    return __builtin_bit_cast(float, u << 16);
}
__device__ __forceinline__ float bfhi(unsigned int u) {
    return __builtin_bit_cast(float, u & 0xffff0000u);
}
__device__ __forceinline__ float sigmoidf_(float z) {
    return 1.0f / (1.0f + __expf(-z));
}
__device__ __forceinline__ bf16x8 ld_bf8(const unsigned short* p) {
    return __builtin_bit_cast(bf16x8, *(const us8*)p);
}
__device__ __forceinline__ bf16x8 pack8(float4 a, float4 b) {
    us8 u;
    u[0] = f2bf(a.x); u[1] = f2bf(a.y); u[2] = f2bf(a.z); u[3] = f2bf(a.w);
    u[4] = f2bf(b.x); u[5] = f2bf(b.y); u[6] = f2bf(b.z); u[7] = f2bf(b.w);
    return __builtin_bit_cast(bf16x8, u);
}

// ---------------------------------------------------------------------------
// Phase A: pair tensors for y3 (verified round 4/5).
// ---------------------------------------------------------------------------
__global__ __launch_bounds__(256) void phaseA_kernel(
    const float* __restrict__ x2, const float* __restrict__ W1,
    const float* __restrict__ b1,
    float* __restrict__ wsA, unsigned short* __restrict__ wsB,
    unsigned short* __restrict__ wsC)
{
    __shared__ float xr[4][32];
    const int t = threadIdx.x;
    if (t < 128) {
        const int pr2 = t >> 5, c = t & 31;
        const int gg = blockIdx.x * 4 + pr2;
        const int bb = gg / 2304, pp2 = gg % 2304, P = pp2 / 48, Q = pp2 % 48;
        const float* base = x2 + (size_t)bb * 36864;
        xr[pr2][c] = (c < 16) ? base[(P * 48 + Q) * 16 + c]
                              : base[(Q * 48 + P) * 16 + (c - 16)];
    }
    __syncthreads();
    const int pr = t >> 6, h = t & 63;
    const int g = blockIdx.x * 4 + pr;
    float a = b1[h], bacc = 0.f, cacc = 0.f;
#pragma unroll
    for (int c = 0; c < 16; ++c) {
        const float xpq = xr[pr][c], xqp = xr[pr][16 + c];
        a    += xpq * W1[(  0 + c) * 64 + h] + xqp * W1[( 64 + c) * 64 + h];
        bacc += xpq * W1[( 32 + c) * 64 + h] + xqp * W1[( 96 + c) * 64 + h];
        cacc += xpq * W1[(128 + c) * 64 + h] + xqp * W1[(160 + c) * 64 + h];
    }
    const size_t o = (size_t)g * 64 + h;
    wsA[o] = a;
    wsB[o] = f2bf(bacc);
    wsC[o] = f2bf(cacc);
}

// ---------------------------------------------------------------------------
// y3 (verified round 5): 2304 blocks x 192 thr, 4 tiles each, barrier-free.
// ---------------------------------------------------------------------------
__global__ __launch_bounds__(192, 3) void y3_kernel(
    const float* __restrict__ x3,
    const float* __restrict__ W1, const float* __restrict__ W2,
    const float* __restrict__ b2,
    const float* __restrict__ wsA,
    const unsigned short* __restrict__ wsB,
    const unsigned short* __restrict__ wsC,
    float* __restrict__ out)
{
    __shared__ __align__(16) unsigned short w1t[64 * 104];   // [h][kk], one-time
    const int t = threadIdx.x;
    const int w = t >> 6, lane = t & 63, lr = lane & 15, lg = lane >> 4;

#pragma unroll
    for (int p = 0; p < 16; ++p) {
        const int e = p * 192 + t;
        const int h = e & 63, kk = (e >> 6) * 2;
        const int r0 = 16 + ((kk >> 4) << 5) + (kk & 15);
        *(unsigned int*)(w1t + h * 104 + kk) =
            pk2(W1[r0 * 64 + h], W1[(r0 + 1) * 64 + h]);
    }
    __syncthreads();   // only barrier in the kernel

    bf16x8 w1f[4][3];
#pragma unroll
    for (int n = 0; n < 4; ++n)
#pragma unroll
        for (int ks = 0; ks < 3; ++ks)
            w1f[n][ks] = ld_bf8(w1t + (16 * n + lr) * 104 + 32 * ks + 8 * lg);

    bf16x8 w2f[2];
#pragma unroll
    for (int m = 0; m < 2; ++m) {
        us8 u;
#pragma unroll
        for (int e = 0; e < 8; ++e) {
            const int ch = 16 * (e >> 1) + 4 * lg + 2 * (e & 1) + m;
            u[e] = f2bf(W2[ch * 16 + lr]);
        }
        w2f[m] = __builtin_bit_cast(bf16x8, u);
    }
    const float4 b2v = *(const float4*)(b2 + 4 * lg);
    const int row = 16 * w + lr;
    const int c0 = 8 * (lg & 1);
    const bool hi = (lg >> 1) != 0;

    for (int it = 0; it < 4; ++it) {
        const int g = blockIdx.x * 4 + it;
        const int b = g / 2304, pp = g % 2304, i = pp / 48, j = pp % 48;
        const float* xb3 = x3 + (size_t)b * 1769472;
        const int sb0 = i * 36864 + j * 768 + row * 16;
        const int sb1 = i * 36864 + row * 768 + j * 16;
        const int sb2 = j * 36864 + i * 768 + row * 16;
        const int sb3 = row * 36864 + i * 768 + j * 16;
        const int sb4 = j * 36864 + row * 768 + i * 16;
        const int sb5 = row * 36864 + j * 768 + i * 16;
        const float* p0 = xb3 + (hi ? sb1 : sb0) + c0;
        const float* p1 = xb3 + (hi ? sb3 : sb2) + c0;
        const float* p2 = xb3 + (hi ? sb5 : sb4) + c0;
        const bf16x8 xf0 = pack8(*(const float4*)p0, *(const float4*)(p0 + 4));
        const bf16x8 xf1 = pack8(*(const float4*)p1, *(const float4*)(p1 + 4));
        const bf16x8 xf2 = pack8(*(const float4*)p2, *(const float4*)(p2 + 4));

        f32x4 acc[4];
#pragma unroll
        for (int n = 0; n < 4; ++n) {
            acc[n] = f32x4{0.f, 0.f, 0.f, 0.f};
            acc[n] = __builtin_amdgcn_mfma_f32_16x16x32_bf16(w1f[n][0], xf0, acc[n], 0, 0, 0);
            acc[n] = __builtin_amdgcn_mfma_f32_16x16x32_bf16(w1f[n][1], xf1, acc[n], 0, 0, 0);
            acc[n] = __builtin_amdgcn_mfma_f32_16x16x32_bf16(w1f[n][2], xf2, acc[n], 0, 0, 0);
        }
        const size_t baseB = ((size_t)((b * 48 + i) * 48 + row)) * 64 + 4 * lg;
        const size_t baseC = ((size_t)((b * 48 + j) * 48 + row)) * 64 + 4 * lg;
        const size_t baseA = ((size_t)((b * 48 + i) * 48 + j)) * 64 + 4 * lg;
#pragma unroll
        for (int n = 0; n < 4; ++n) {
            const uint2 Bu = *(const uint2*)(wsB + baseB + 16 * n);
            const uint2 Cu = *(const uint2*)(wsC + baseC + 16 * n);
            const float4 Au = *(const float4*)(wsA + baseA + 16 * n);
            acc[n][0] = fmaxf(acc[n][0] + Au.x + bflo(Bu.x) + bflo(Cu.x), 0.f);
            acc[n][1] = fmaxf(acc[n][1] + Au.y + bfhi(Bu.x) + bfhi(Cu.x), 0.f);
            acc[n][2] = fmaxf(acc[n][2] + Au.z + bflo(Bu.y) + bflo(Cu.y), 0.f);
            acc[n][3] = fmaxf(acc[n][3] + Au.w + bfhi(Bu.y) + bfhi(Cu.y), 0.f);
        }
        bf16x8 hf[2];
#pragma unroll
        for (int m = 0; m < 2; ++m) {
            us8 u;
#pragma unroll
            for (int e = 0; e < 8; ++e)
                u[e] = f2bf(acc[e >> 1][2 * (e & 1) + m]);
            hf[m] = __builtin_bit_cast(bf16x8, u);
        }
        f32x4 o2 = {0.f, 0.f, 0.f, 0.f};
        o2 = __builtin_amdgcn_mfma_f32_16x16x32_bf16(w2f[0], hf[0], o2, 0, 0, 0);
        o2 = __builtin_amdgcn_mfma_f32_16x16x32_bf16(w2f[1], hf[1], o2, 0, 0, 0);
        float4 ov;
        ov.x = sigmoidf_(o2[0] + b2v.x);
        ov.y = sigmoidf_(o2[1] + b2v.y);
        ov.z = sigmoidf_(o2[2] + b2v.z);
        ov.w = sigmoidf_(o2[3] + b2v.w);
        *(float4*)(out + (size_t)g * 768 + row * 16 + 4 * lg) = ov;
    }
}

// ---------------------------------------------------------------------------
// red3 (verified round 5 + unroll-8 for outstanding loads)
// ---------------------------------------------------------------------------
__global__ __launch_bounds__(256) void red3_kernel(
    const float* __restrict__ x3, unsigned short* __restrict__ red3)
{
    const int slot = blockIdx.x * 256 + threadIdx.x;
    const int c = slot & 15;
    const int q = slot >> 4;          // pi*48 + j, pi = b*48+i
    const int j = q % 48, pi = q / 48, i = pi % 48;
    const float* p = x3 + (size_t)q * 768 + c;
    float ex = -__builtin_inff(), fa = __builtin_inff();
    const bool mij = (i != j);
#pragma unroll 8
    for (int k = 0; k < 48; ++k) {
        const bool m = mij & (k != i) & (k != j);
        const float v = p[k * 16];
        ex = fmaxf(ex, m ? v : 0.f);
        fa = fminf(fa, m ? v : 1.f);
    }
    *(unsigned int*)(red3 + (size_t)q * 32 + 2 * c) = pk2(ex, fa);
}

// ---------------------------------------------------------------------------
// y2 MLP (verified round 5)
// ---------------------------------------------------------------------------
__global__ __launch_bounds__(192, 3) void y2_mlp_kernel(
    const float* __restrict__ x1, const float* __restrict__ x2,
    const float* __restrict__ W1, const float* __restrict__ b1,
    const float* __restrict__ W2, const float* __restrict__ b2,
    const unsigned short* __restrict__ red3, float* __restrict__ out)
{
    __shared__ __align__(16) unsigned short w1t[64 * 136];
    const int t = threadIdx.x;
    const int w = t >> 6, lane = t & 63, lr = lane & 15, lg = lane >> 4;

#pragma unroll
    for (int p = 0; p < 22; ++p) {
        const int e = p * 192 + t;
        if (e < 4096) {
            const int h = e & 63, k2 = e >> 6;
            *(unsigned int*)(w1t + h * 136 + 2 * k2) =
                pk2(W1[(2 * k2) * 64 + h], W1[(2 * k2 + 1) * 64 + h]);
        }
    }
    __syncthreads();

    bf16x8 w1f[4][4];
#pragma unroll
    for (int n = 0; n < 4; ++n)
#pragma unroll
        for (int ks = 0; ks < 4; ++ks)
            w1f[n][ks] = ld_bf8(w1t + (16 * n + lr) * 136 + 32 * ks + 8 * lg);

    bf16x8 w2f[2];
#pragma unroll
    for (int m = 0; m < 2; ++m) {
        us8 u;
#pragma unroll
        for (int e = 0; e < 8; ++e) {
            const int ch = 16 * (e >> 1) + 4 * lg + 2 * (e & 1) + m;
            u[e] = f2bf(W2[ch * 16 + lr]);
        }
        w2f[m] = __builtin_bit_cast(bf16x8, u);
    }
    float4 b1v[4];
#pragma unroll
    for (int n = 0; n < 4; ++n) b1v[n] = *(const float4*)(b1 + 16 * n + 4 * lg);
    const float4 b2v = *(const float4*)(b2 + 4 * lg);

    const int bq = blockIdx.x;                 // b*48 + i
    const int b = bq / 48, i = bq % 48;
    const float* x2b = x2 + (size_t)b * 36864;
    const int row = 16 * w + lr;               // = j
    const int j = row;
    const int c0 = 8 * (lg & 1);
    const bool hi = (lg >> 1) != 0;

    const float* a0 = hi ? (x2b + (i * 48 + j) * 16 + c0) : (x1 + (b * 48 + i) * 16 + c0);
    const float* a2 = hi ? (x2b + (j * 48 + i) * 16 + c0) : (x1 + (b * 48 + j) * 16 + c0);
    const unsigned short* r1 = red3 + ((size_t)(b * 48 + i) * 48 + j) * 32 + (hi ? 16 : 0) + c0;
    const unsigned short* r3 = red3 + ((size_t)(b * 48 + j) * 48 + i) * 32 + (hi ? 16 : 0) + c0;

    const bf16x8 xf0 = pack8(*(const float4*)a0, *(const float4*)(a0 + 4));
    const bf16x8 xf1 = ld_bf8(r1);
    const bf16x8 xf2 = pack8(*(const float4*)a2, *(const float4*)(a2 + 4));
    const bf16x8 xf3 = ld_bf8(r3);

    f32x4 acc[4];
#pragma unroll
    for (int n = 0; n < 4; ++n) {
        acc[n] = f32x4{0.f, 0.f, 0.f, 0.f};
        acc[n] = __builtin_amdgcn_mfma_f32_16x16x32_bf16(w1f[n][0], xf0, acc[n], 0, 0, 0);
        acc[n] = __builtin_amdgcn_mfma_f32_16x16x32_bf16(w1f[n][1], xf1, acc[n], 0, 0, 0);
        acc[n] = __builtin_amdgcn_mfma_f32_16x16x32_bf16(w1f[n][2], xf2, acc[n], 0, 0, 0);
        acc[n] = __builtin_amdgcn_mfma_f32_16x16x32_bf16(w1f[n][3], xf3, acc[n], 0, 0, 0);
    }
#pragma unroll
    for (int n = 0; n < 4; ++n) {
        acc[n][0] = fmaxf(acc[n][0] + b1v[n].x, 0.f);
        acc[n][1] = fmaxf(acc[n][1] + b1v[n].y, 0.f);
        acc[n][2] = fmaxf(acc[n][2] + b1v[n].z, 0.f);
        acc[n][3] = fmaxf(acc[n][3] + b1v[n].w, 0.f);
    }
    bf16x8 hf[2];
#pragma unroll
    for (int m = 0; m < 2; ++m) {
        us8 u;
#pragma unroll
        for (int e = 0; e < 8; ++e)
            u[e] = f2bf(acc[e >> 1][2 * (e & 1) + m]);
        hf[m] = __builtin_bit_cast(bf16x8, u);
    }
    f32x4 o2 = {0.f, 0.f, 0.f, 0.f};
    o2 = __builtin_amdgcn_mfma_f32_16x16x32_bf16(w2f[0], hf[0], o2, 0, 0, 0);
    o2 = __builtin_amdgcn_mfma_f32_16x16x32_bf16(w2f[1], hf[1], o2, 0, 0, 0);
    float4 ov;
    ov.x = sigmoidf_(o2[0] + b2v.x);
    ov.y = sigmoidf_(o2[1] + b2v.y);
    ov.z = sigmoidf_(o2[2] + b2v.z);
    ov.w = sigmoidf_(o2[3] + b2v.w);
    *(float4*)(out + ((size_t)bq * 48 + row) * 16 + 4 * lg) = ov;
}

// ---------------------------------------------------------------------------
// y0 + y1 (round-6 rewrite).  Grid = 5 blocks x 192 threads.
// Blocks 0..3: y1 for b = blockIdx.  Phase 1: red2 = masked reduce over jj of
// x2[b,i,jj,c] into LDS (768 slots, 4/thread, unroll-8).  Phase 2: swapped
// MFMA MLP, K=64: xf0 = [x0_b | x1_{b,i}], xf1 = red2 (interleaved ex/fa).
// Block 4: y0 cooperative: 64 threads reduce x1 over n (no mask), then two
// tiny LDS MLP phases.  No per-thread arrays -> no spill; launch_bounds(192,1).
// ---------------------------------------------------------------------------
__global__ __launch_bounds__(192, 1) void y01_kernel(
    const float* __restrict__ x0, const float* __restrict__ x1,
    const float* __restrict__ x2,
    const float* __restrict__ W1_0, const float* __restrict__ b1_0,
    const float* __restrict__ W2_0, const float* __restrict__ b2_0,
    const float* __restrict__ W1_1, const float* __restrict__ b1_1,
    const float* __restrict__ W2_1, const float* __restrict__ b2_1,
    float* __restrict__ out)
{
    const int t = threadIdx.x;
    if (blockIdx.x < 4) {
        // ------------------- y1 -------------------
        __shared__ __align__(16) unsigned short w1t[64 * 72];
        __shared__ __align__(16) unsigned short red2l[48 * 32];
        const int b = blockIdx.x;
        // Stage W1_1^T: [64 cin][64 h] -> w1t[h][72] bf16 (2048 uints, 11 passes)
#pragma unroll
        for (int p = 0; p < 11; ++p) {
            const int e = p * 192 + t;
            if (e < 2048) {
                const int h = e & 63, k2 = e >> 6;
                *(unsigned int*)(w1t + h * 72 + 2 * k2) =
                    pk2(W1_1[(2 * k2) * 64 + h], W1_1[(2 * k2 + 1) * 64 + h]);
            }
        }
        // red2 into LDS: slot s = i*16+c, 4 slots/thread
        const float* x2b = x2 + (size_t)b * 36864;
#pragma unroll
        for (int s4 = 0; s4 < 4; ++s4) {
            const int s = t + 192 * s4;            // 0..767
            const int i = s >> 4, c = s & 15;
            const float* p = x2b + i * 768 + c;
            float ex = -__builtin_inff(), fa = __builtin_inff();
#pragma unroll 8
            for (int jj = 0; jj < 48; ++jj) {
                const bool m = (jj != i);
                const float v = p[jj * 16];
                ex = fmaxf(ex, m ? v : 0.f);
                fa = fminf(fa, m ? v : 1.f);
            }
            *(unsigned int*)(red2l + i * 32 + 2 * c) = pk2(ex, fa);
        }
        __syncthreads();

        const int w = t >> 6, lane = t & 63, lr = lane & 15, lg = lane >> 4;
        const int i = 16 * w + lr;                 // row within b
        const int rho = b * 48 + i;
        bf16x8 w1f[4][2];
#pragma unroll
        for (int n = 0; n < 4; ++n)
#pragma unroll
            for (int ks = 0; ks < 2; ++ks)
                w1f[n][ks] = ld_bf8(w1t + (16 * n + lr) * 72 + 32 * ks + 8 * lg);
        bf16x8 w2f[2];
#pragma unroll
        for (int m = 0; m < 2; ++m) {
            us8 u;
#pragma unroll
            for (int e = 0; e < 8; ++e) {
                const int ch = 16 * (e >> 1) + 4 * lg + 2 * (e & 1) + m;
                u[e] = f2bf(W2_1[ch * 16 + lr]);
            }
            w2f[m] = __builtin_bit_cast(bf16x8, u);
        }
        float4 b1v[4];
#pragma unroll
        for (int n = 0; n < 4; ++n) b1v[n] = *(const float4*)(b1_1 + 16 * n + 4 * lg);
        const float4 b2v = *(const float4*)(b2_1 + 4 * lg);

        const int c0 = 8 * (lg & 1);
        const float* a0 = (lg < 2) ? (x0 + b * 16 + c0) : (x1 + rho * 16 + c0);
        const bf16x8 xf0 = pack8(*(const float4*)a0, *(const float4*)(a0 + 4));
        const bf16x8 xf1 = ld_bf8(red2l + i * 32 + 8 * lg);

        f32x4 acc[4];
#pragma unroll
        for (int n = 0; n < 4; ++n) {
            acc[n] = f32x4{0.f, 0.f, 0.f, 0.f};
            acc[n] = __builtin_amdgcn_mfma_f32_16x16x32_bf16(w1f[n][0], xf0, acc[n], 0, 0, 0);
            acc[n] = __builtin_amdgcn_mfma_f32_16x16x32_bf16(w1f[n][1], xf1, acc[n], 0, 0, 0);
        }
#pragma unroll
        for (int n = 0; n < 4; ++n) {
            acc[n][0] = fmaxf(acc[n][0] + b1v[n].x, 0.f);
            acc[n][1] = fmaxf(acc[n][1] + b1v[n].y, 0.f);
            acc[n][2] = fmaxf(acc[n][2] + b1v[n].z, 0.f);
            acc[n][3] = fmaxf(acc[n][3] + b1v[n].w, 0.f);
        }
        bf16x8 hf[2];
#pragma unroll
        for (int m = 0; m < 2; ++m) {
            us8 u;
#pragma unroll
            for (int e = 0; e < 8; ++e)
                u[e] = f2bf(acc[e >> 1][2 * (e & 1) + m]);
            hf[m] = __builtin_bit_cast(bf16x8, u);
        }
        f32x4 o2 = {0.f, 0.f, 0.f, 0.f};
        o2 = __builtin_amdgcn_mfma_f32_16x16x32_bf16(w2f[0], hf[0], o2, 0, 0, 0);
        o2 = __builtin_amdgcn_mfma_f32_16x16x32_bf16(w2f[1], hf[1], o2, 0, 0, 0);
        float4 ov;
        ov.x = sigmoidf_(o2[0] + b2v.x);
        ov.y = sigmoidf_(o2[1] + b2v.y);
        ov.z = sigmoidf_(o2[2] + b2v.z);
        ov.w = sigmoidf_(o2[3] + b2v.w);
        *(float4*)(out + 64 + (size_t)rho * 16 + 4 * lg) = ov;   // y1 region
    } else {
        // ------------------- y0 -------------------
        __shared__ float t0l[4][56];   // [b][48 ch], padded
        __shared__ float hl[4][72];    // [b][64 h], padded
        if (t < 64) {
            const int b = t >> 4, c = t & 15;
            const float* p = x1 + b * 768 + c;
            float ex = -__builtin_inff(), fa = __builtin_inff();
#pragma unroll 8
            for (int n = 0; n < 48; ++n) {
                const float v = p[n * 16];
                ex = fmaxf(ex, v);
                fa = fminf(fa, v);
            }
            t0l[b][c] = x0[b * 16 + c];
            t0l[b][16 + 2 * c] = ex;
            t0l[b][17 + 2 * c] = fa;
        }
        __syncthreads();
        if (t < 64) {
            const int h = t;
            float ac0 = b1_0[h], ac1 = ac0, ac2 = ac0, ac3 = ac0;
#pragma unroll
            for (int c = 0; c < 48; ++c) {
                const float wv = W1_0[c * 64 + h];
                ac0 = fmaf(t0l[0][c], wv, ac0);
                ac1 = fmaf(t0l[1][c], wv, ac1);
                ac2 = fmaf(t0l[2][c], wv, ac2);
                ac3 = fmaf(t0l[3][c], wv, ac3);
            }
            hl[0][h] = fmaxf(ac0, 0.f);
            hl[1][h] = fmaxf(ac1, 0.f);
            hl[2][h] = fmaxf(ac2, 0.f);
            hl[3][h] = fmaxf(ac3, 0.f);
        }
        __syncthreads();
        if (t < 64) {
            const int b = t >> 4, o = t & 15;
            float a = b2_0[o];
#pragma unroll
            for (int h = 0; h < 64; ++h)
                a = fmaf(hl[b][h], W2_0[h * 16 + o], a);
            out[b * 16 + o] = sigmoidf_(a);
        }
    }
}

// ---------------------------------------------------------------------------
// Fallback paths (verified round 1/4), used only if workspace too small.
// ---------------------------------------------------------------------------
template <int NK>
__device__ __forceinline__ void mlp_head(
    const unsigned short* lds_in, const unsigned short* lds_w1t,
    const unsigned short* lds_w2t, const float* lds_b1, const float* lds_b2,
    unsigned short* lds_h, float* outp)
{
    constexpr int S = NK * 32 + 8;
    const int t = threadIdx.x;
    const int w = t >> 6, lr = t & 15, lg = (t >> 4) & 3;
    f32x4 acc0 = {0.f, 0.f, 0.f, 0.f};
    f32x4 acc1 = acc0, acc2 = acc0, acc3 = acc0;
    const unsigned short* pa = lds_in + (16 * w + lr) * S + lg * 8;
    const unsigned short* pb = lds_w1t + lr * S + lg * 8;
#pragma unroll
    for (int ks = 0; ks < NK; ++ks) {
        bf16x8 a = ld_bf8(pa + ks * 32);
        acc0 = __builtin_amdgcn_mfma_f32_16x16x32_bf16(a, ld_bf8(pb + 0 * 16 * S + ks * 32), acc0, 0, 0, 0);
        acc1 = __builtin_amdgcn_mfma_f32_16x16x32_bf16(a, ld_bf8(pb + 1 * 16 * S + ks * 32), acc1, 0, 0, 0);
        acc2 = __builtin_amdgcn_mfma_f32_16x16x32_bf16(a, ld_bf8(pb + 2 * 16 * S + ks * 32), acc2, 0, 0, 0);
        acc3 = __builtin_amdgcn_mfma_f32_16x16x32_bf16(a, ld_bf8(pb + 3 * 16 * S + ks * 32), acc3, 0, 0, 0);
    }
    const int hrow = 16 * w + lg * 4;
#pragma unroll
    for (int r = 0; r < 4; ++r) {
        lds_h[(hrow + r) * 72 +  0 + lr] = f2bf(fmaxf(acc0[r] + lds_b1[ 0 + lr], 0.f));
        lds_h[(hrow + r) * 72 + 16 + lr] = f2bf(fmaxf(acc1[r] + lds_b1[16 + lr], 0.f));
        lds_h[(hrow + r) * 72 + 32 + lr] = f2bf(fmaxf(acc2[r] + lds_b1[32 + lr], 0.f));
        lds_h[(hrow + r) * 72 + 48 + lr] = f2bf(fmaxf(acc3[r] + lds_b1[48 + lr], 0.f));
    }
    __syncthreads();
    f32x4 o = {0.f, 0.f, 0.f, 0.f};
#pragma unroll
    for (int ks = 0; ks < 2; ++ks) {
        bf16x8 a = ld_bf8(lds_h + (16 * w + lr) * 72 + ks * 32 + lg * 8);
        bf16x8 b = ld_bf8(lds_w2t + lr * 72 + ks * 32 + lg * 8);
        o = __builtin_amdgcn_mfma_f32_16x16x32_bf16(a, b, o, 0, 0, 0);
    }
    const float b2v = lds_b2[lr];
#pragma unroll
    for (int r = 0; r < 4; ++r)
        outp[(hrow + r) * 16 + lr] = sigmoidf_(o[r] + b2v);
}

__global__ __launch_bounds__(192) void y3_fallback_kernel(
    const float* __restrict__ x2, const float* __restrict__ x3,
    const float* __restrict__ W1, const float* __restrict__ b1,
    const float* __restrict__ W2, const float* __restrict__ b2,
    float* __restrict__ out)
{
    __shared__ __align__(16) unsigned short lds_in[48 * 200];
    __shared__ __align__(16) unsigned short lds_w1t[64 * 200];
    __shared__ __align__(16) unsigned short lds_w2t[16 * 72];
    __shared__ __align__(16) unsigned short lds_h[48 * 72];
    __shared__ float lds_b1[64];
    __shared__ float lds_b2[16];
    const int t = threadIdx.x;
#pragma unroll 4
    for (int p = 0; p < 32; ++p) {
        int e = p * 192 + t;
        int h = e & 63, c2 = e >> 6;
        *(unsigned int*)(lds_w1t + h * 200 + 2 * c2) =
            pk2(W1[(2 * c2) * 64 + h], W1[(2 * c2 + 1) * 64 + h]);
    }
    for (int p = 0; p < 3; ++p) {
        int e = p * 192 + t;
        if (e < 512) {
            int n = e & 15, k2 = e >> 4;
            *(unsigned int*)(lds_w2t + n * 72 + 2 * k2) =
                pk2(W2[(2 * k2) * 16 + n], W2[(2 * k2 + 1) * 16 + n]);
        }
    }
    if (t < 64) lds_b1[t] = b1[t];
    if (t < 16) lds_b2[t] = b2[t];
    const int k = t >> 2, c4 = (t & 3) * 4;
#define STAGE3(PTR, BASE, KSTR, CH) do {                                       \
        const float4 v = *(const float4*)((PTR) + (BASE) + k * (KSTR) + c4);   \
        *(uint2*)(lds_in + k * 200 + (CH) + c4) =                              \
            make_uint2(pk2(v.x, v.y), pk2(v.z, v.w));                          \
    } while (0)
    for (int it = 0; it < 9; ++it) {
        const int g = blockIdx.x * 9 + it;
        const int b = g / 2304, rg = g % 2304, i = rg / 48, j = rg % 48;
        const float* xb2 = x2 + b * 36864;
        const float* xb3 = x3 + b * 1769472;
        __syncthreads();
        STAGE3(xb2, i * 768 + j * 16, 0,       0);
        STAGE3(xb3, i * 36864 + j * 768, 16,   16);
        STAGE3(xb2, i * 768, 16,               32);
        STAGE3(xb3, i * 36864 + j * 16, 768,   48);
        STAGE3(xb2, j * 768 + i * 16, 0,       64);
        STAGE3(xb3, j * 36864 + i * 768, 16,   80);
        STAGE3(xb2, i * 16, 768,               96);
        STAGE3(xb3, i * 768 + j * 16, 36864,   112);
        STAGE3(xb2, j * 768, 16,               128);
        STAGE3(xb3, j * 36864 + i * 16, 768,   144);
        STAGE3(xb2, j * 16, 768,               160);
        STAGE3(xb3, j * 768 + i * 16, 36864,   176);
        __syncthreads();
        mlp_head<6>(lds_in, lds_w1t, lds_w2t, lds_b1, lds_b2, lds_h,
                    out + (size_t)g * 768);
    }
#undef STAGE3
}

__global__ __launch_bounds__(192) void y2_kernel(
    const float* __restrict__ x1, const float* __restrict__ x2,
    const float* __restrict__ x3,
    const float* __restrict__ W1, const float* __restrict__ b1,
    const float* __restrict__ W2, const float* __restrict__ b2,
    float* __restrict__ out)
{
    __shared__ __align__(16) unsigned short lds_in[48 * 136];
    __shared__ __align__(16) unsigned short lds_w1t[64 * 136];
    __shared__ __align__(16) unsigned short lds_w2t[16 * 72];
    __shared__ __align__(16) unsigned short lds_h[48 * 72];
    __shared__ float lds_b1[64];
    __shared__ float lds_b2[16];
    const int t = threadIdx.x;
    const int b = blockIdx.x / 48, i = blockIdx.x % 48;
#pragma unroll 2
    for (int p = 0; p < 22; ++p) {
        int e = p * 192 + t;
        if (e < 4096) {
            int h = e & 63, c2 = e >> 6;
            *(unsigned int*)(lds_w1t + h * 136 + 2 * c2) =
                pk2(W1[(2 * c2) * 64 + h], W1[(2 * c2 + 1) * 64 + h]);
        }
    }
    for (int p = 0; p < 3; ++p) {
        int e = p * 192 + t;
        if (e < 512) {
            int n = e & 15, k2 = e >> 4;
            *(unsigned int*)(lds_w2t + n * 72 + 2 * k2) =
                pk2(W2[(2 * k2) * 16 + n], W2[(2 * k2 + 1) * 16 + n]);
        }
    }
    if (t < 64) lds_b1[t] = b1[t];
    if (t < 16) lds_b2[t] = b2[t];
    const int j = t >> 2, c4 = (t & 3) * 4;
    const float* xb2 = x2 + b * 36864;
#define STAGE2(PTR, BASE, JSTR, CH) do {                                       \
        const float4 v = *(const float4*)((PTR) + (BASE) + j * (JSTR) + c4);   \
        *(uint2*)(lds_in + j * 136 + (CH) + c4) =                              \
            make_uint2(pk2(v.x, v.y), pk2(v.z, v.w));                          \
    } while (0)
    STAGE2(x1, b * 768 + i * 16, 0,  0);
    STAGE2(xb2, i * 768, 16,         16);
    STAGE2(x1, b * 768, 16,          64);
    STAGE2(xb2, i * 16, 768,         80);
#undef STAGE2
    {
        const float* pa = x3 + b * 1769472 + (i * 48 + j) * 768 + c4;
        const float* pb = x3 + b * 1769472 + (j * 48 + i) * 768 + c4;
        float exa[4], faa[4], exb[4], fab[4];
#pragma unroll
        for (int u = 0; u < 4; ++u) {
            exa[u] = -__builtin_inff(); faa[u] = __builtin_inff();
            exb[u] = -__builtin_inff(); fab[u] = __builtin_inff();
        }
        for (int kk = 0; kk < 48; ++kk) {
            const bool m = (i != j) & (i != kk) & (j != kk);
            const float4 va = *(const float4*)(pa + kk * 16);
            const float4 vb = *(const float4*)(pb + kk * 16);
            const float av[4] = {va.x, va.y, va.z, va.w};
            const float bv[4] = {vb.x, vb.y, vb.z, vb.w};
#pragma unroll
            for (int u = 0; u < 4; ++u) {
                exa[u] = fmaxf(exa[u], m ? av[u] : 0.f);
                faa[u] = fminf(faa[u], m ? av[u] : 1.f);
                exb[u] = fmaxf(exb[u], m ? bv[u] : 0.f);
                fab[u] = fminf(fab[u], m ? bv[u] : 1.f);
            }
        }
#pragma unroll
        for (int u = 0; u < 4; ++u) {
            const int c = c4 + u;
            *(unsigned int*)(lds_in + j * 136 + 32 + 2 * c) = pk2(exa[u], faa[u]);
            *(unsigned int*)(lds_in + j * 136 + 96 + 2 * c) = pk2(exb[u], fab[u]);
        }
    }
    __syncthreads();
    mlp_head<4>(lds_in, lds_w1t, lds_w2t, lds_b1, lds_b2, lds_h,
                out + (size_t)blockIdx.x * 768);
}

// ---------------------------------------------------------------------------
extern "C" void kernel_launch(void* const* d_in, const int* in_sizes, int n_in,
                              void* d_out, int out_size, void* d_ws, size_t ws_size,
                              hipStream_t stream) {
    (void)in_sizes; (void)n_in; (void)out_size;
    const float* x0 = (const float*)d_in[0];
    const float* x1 = (const float*)d_in[1];
    const float* x2 = (const float*)d_in[2];
    const float* x3 = (const float*)d_in[3];
    const float* W1_0 = (const float*)d_in[4];
    const float* b1_0 = (const float*)d_in[5];
    const float* W2_0 = (const float*)d_in[6];
    const float* b2_0 = (const float*)d_in[7];
    const float* W1_1 = (const float*)d_in[8];
    const float* b1_1 = (const float*)d_in[9];
    const float* W2_1 = (const float*)d_in[10];
    const float* b2_1 = (const float*)d_in[11];
    const float* W1_2 = (const float*)d_in[12];
    const float* b1_2 = (const float*)d_in[13];
    const float* W2_2 = (const float*)d_in[14];
    const float* b2_2 = (const float*)d_in[15];
    const float* W1_3 = (const float*)d_in[16];
    const float* b1_3 = (const float*)d_in[17];
    const float* W2_3 = (const float*)d_in[18];
    const float* b2_3 = (const float*)d_in[19];
    float* out = (float*)d_out;

    // Output layout: y0 [0,64) | y1 [64,3136) | y2 [3136,150592) | y3 [150592,...)
    // ws layout (shorts): A fp32 [2*NPAIR] | B [NPAIR] | C [NPAIR] | red3 [NRED3]
    const size_t ws_need = (size_t)8 * NPAIR + (size_t)2 * NRED3;
    if (ws_size >= ws_need) {
        float* wsA = (float*)d_ws;
        unsigned short* wsB = (unsigned short*)d_ws + 2 * NPAIR;
        unsigned short* wsC = wsB + NPAIR;
        unsigned short* red3 = (unsigned short*)d_ws + 4 * NPAIR;
        phaseA_kernel<<<2304, 256, 0, stream>>>(x2, W1_3, b1_3, wsA, wsB, wsC);
        y3_kernel<<<2304, 192, 0, stream>>>(x3, W1_3, W2_3, b2_3,
                                            wsA, wsB, wsC, out + 150592);
        red3_kernel<<<576, 256, 0, stream>>>(x3, red3);
        y2_mlp_kernel<<<192, 192, 0, stream>>>(x1, x2, W1_2, b1_2, W2_2, b2_2,
                                               red3, out + 3136);
    } else {
        y3_fallback_kernel<<<1024, 192, 0, stream>>>(x2, x3, W1_3, b1_3, W2_3, b2_3,
                                                     out + 150592);
        y2_kernel<<<192, 192, 0, stream>>>(x1, x2, x3, W1_2, b1_2, W2_2, b2_2,
                                           out + 3136);
    }
    y01_kernel<<<5, 192, 0, stream>>>(x0, x1, x2, W1_0, b1_0, W2_0, b2_0,
                                      W1_1, b1_1, W2_1, b2_1, out);
}